// Round 2
// baseline (1471.539 us; speedup 1.0000x reference)
//
#include <hip/hip_runtime.h>
#include <hip/hip_bf16.h>

#define Tn 1024
#define Bn 64
#define En 128
#define G4 512
#define NEGV -10000.0f

typedef _Float16 h8v __attribute__((ext_vector_type(8)));
typedef short bh8 __attribute__((ext_vector_type(8)));
typedef float fl4 __attribute__((ext_vector_type(4)));
typedef int i8v __attribute__((ext_vector_type(8)));

// ---------- bf16 helpers ----------
__device__ __forceinline__ float bf2f(unsigned short u) {
    unsigned int v = ((unsigned int)u) << 16;
    float f;
    __builtin_memcpy(&f, &v, 4);
    return f;
}
__device__ __forceinline__ unsigned short f2bf(float f) {
    unsigned int u;
    __builtin_memcpy(&u, &f, 4);
    u = (u + 0x7fffu + ((u >> 16) & 1u)) >> 16;
    return (unsigned short)u;
}
__device__ __forceinline__ float asf(unsigned int u) {
    float f;
    __builtin_memcpy(&f, &u, 4);
    return f;
}

// ---------- fp8 e4m3fn encode ----------
__device__ __forceinline__ unsigned char f8enc(float x) {
#if __has_builtin(__builtin_amdgcn_cvt_pk_fp8_f32)
    int pk = __builtin_amdgcn_cvt_pk_fp8_f32(x, 0.0f, 0, false);
    return (unsigned char)(pk & 0xff);
#else
    // manual OCP e4m3fn (RNE): max 448, min normal 2^-6, subnormal step 2^-9
    unsigned u;
    __builtin_memcpy(&u, &x, 4);
    unsigned s = (u >> 31) << 7;
    float a = fabsf(x);
    if (!(a > 0.0f)) return (unsigned char)s;
    if (a >= 464.0f) return (unsigned char)(s | 0x7E);
    if (a < 0.015625f) {                       // subnormal
        int q = (int)rintf(a * 512.0f);        // a / 2^-9 ; q in [0,8] (8 -> min normal)
        return (unsigned char)(s | (unsigned)q);
    }
    int ex;
    (void)frexpf(a, &ex);                      // a = fr * 2^ex, fr in [0.5,1)
    int E = ex - 1;
    float t = ldexpf(a, -E);                   // [1,2)
    int m3 = (int)rintf((t - 1.0f) * 8.0f);    // 0..8
    if (m3 == 8) { m3 = 0; E += 1; }
    if (E > 8) return (unsigned char)(s | 0x7E);
    return (unsigned char)(s | ((unsigned)(E + 7) << 3) | (unsigned)m3);
#endif
}

__device__ __forceinline__ float sigf(float x) { return 1.0f / (1.0f + __expf(-x)); }
__device__ __forceinline__ float tanhfast(float x) { return 1.0f - 2.0f / (1.0f + __expf(2.0f * x)); }

// lgkm-only barrier: LDS visibility without draining vmcnt.
// imm 0xC07F = vmcnt(63) expcnt(7) lgkmcnt(0).
__device__ __forceinline__ void barrier_lds_only() {
    __builtin_amdgcn_s_waitcnt(0xC07F);
    __builtin_amdgcn_s_barrier();
}

// ---------- one LSTM cell update from 4 gate accumulators + packed G ----------
// gx = [i | f<<16] bf16 pair, gy = [g | o<<16] bf16 pair (layout [t][b][j][gate])
__device__ __forceinline__ float lstm_cell(float a0, float a1, float a2, float a3,
                                           unsigned int gx, unsigned int gy,
                                           float ds, float& c) {
    float pi = __builtin_fmaf(a0, ds, asf(gx << 16));
    float pf = __builtin_fmaf(a1, ds, asf(gx & 0xffff0000u));
    float pg = __builtin_fmaf(a2, ds, asf(gy << 16));
    float po = __builtin_fmaf(a3, ds, asf(gy & 0xffff0000u));
    float iv = sigf(pi), fv = sigf(pf), ov = sigf(po);
    float gv = tanhfast(pg);
    c = fv * c + iv * gv;
    return ov * tanhfast(c);
}

// =====================================================================
// K0: one-time weight conversion whh (fp32 [512][128], both dirs) -> fp8 e4m3
// scaled by 64 (keeps w ~ N(0,0.01) in e4m3's normal range).
// =====================================================================
__global__ __launch_bounds__(256) void k_wcvt(
    const float* __restrict__ wf, const float* __restrict__ wb,
    unsigned char* __restrict__ o)
{
    const int i = blockIdx.x * 256 + threadIdx.x;   // 0 .. 131071
    const float v = (i < 65536) ? wf[i] : wb[i - 65536];
    o[i] = f8enc(v * 64.0f);
}

// =====================================================================
// K1: input projection via bf16 MFMA.
// R13 change: G layout is now [t][b][j][gate] (4 ushorts contiguous per j)
// so k_lstm fetches all 4 gate pre-acts with ONE dwordx2 load per dir.
// Only the store index changes; bias indexing (gate-major) untouched.
// =====================================================================
__global__ __launch_bounds__(256) void k_inproj(
    const int* __restrict__ sent, const float* __restrict__ embed,
    const float* __restrict__ w_ih_f, const float* __restrict__ b_ih_f, const float* __restrict__ b_hh_f,
    const float* __restrict__ w_ih_b, const float* __restrict__ b_ih_b, const float* __restrict__ b_hh_b,
    unsigned short* __restrict__ G_f, unsigned short* __restrict__ G_b)
{
    __shared__ unsigned short Asm[128][136];
    __shared__ unsigned short Bsm[128][136];
    const int tid = threadIdx.x;
    const int dir = blockIdx.z;
    const float* w_ih = dir ? w_ih_b : w_ih_f;
    const float* bi   = dir ? b_ih_b : b_ih_f;
    const float* bh   = dir ? b_hh_b : b_hh_f;
    unsigned short* Gout = dir ? G_b : G_f;

    const int mt = blockIdx.x, nt = blockIdx.y;
    const int r0 = mt * 128, n0 = nt * 128;

    const int srow = tid >> 1;
    const int ch = (tid & 1) * 64;
    {
        const int rg = r0 + srow;
        const int tt = rg >> 6, bb = rg & 63;
        const int tok = sent[bb * Tn + tt];
        const float* ar = embed + (size_t)tok * En + ch;
        const float* br = w_ih + (size_t)(n0 + srow) * En + ch;
#pragma unroll
        for (int i = 0; i < 64; i += 4) {
            float4 v = *(const float4*)(ar + i);
            *(unsigned*)&Asm[srow][ch + i]     = (unsigned)f2bf(v.x) | ((unsigned)f2bf(v.y) << 16);
            *(unsigned*)&Asm[srow][ch + i + 2] = (unsigned)f2bf(v.z) | ((unsigned)f2bf(v.w) << 16);
            float4 u = *(const float4*)(br + i);
            *(unsigned*)&Bsm[srow][ch + i]     = (unsigned)f2bf(u.x) | ((unsigned)f2bf(u.y) << 16);
            *(unsigned*)&Bsm[srow][ch + i + 2] = (unsigned)f2bf(u.z) | ((unsigned)f2bf(u.w) << 16);
        }
    }
    __syncthreads();

    const int w = tid >> 6, lane = tid & 63;
    const int ln = lane & 15, lq = lane >> 4;
    const int nwb = w * 32;

    fl4 acc[8][2];
#pragma unroll
    for (int mi = 0; mi < 8; ++mi)
#pragma unroll
        for (int ni = 0; ni < 2; ++ni) acc[mi][ni] = (fl4){0.f, 0.f, 0.f, 0.f};

#pragma unroll
    for (int kt = 0; kt < 4; ++kt) {
        const int kc = kt * 32 + lq * 8;
        bh8 a[8], bf[2];
#pragma unroll
        for (int mi = 0; mi < 8; ++mi) a[mi] = *(const bh8*)&Asm[mi * 16 + ln][kc];
#pragma unroll
        for (int ni = 0; ni < 2; ++ni) bf[ni] = *(const bh8*)&Bsm[nwb + ni * 16 + ln][kc];
#pragma unroll
        for (int mi = 0; mi < 8; ++mi)
#pragma unroll
            for (int ni = 0; ni < 2; ++ni)
                acc[mi][ni] = __builtin_amdgcn_mfma_f32_16x16x32_bf16(a[mi], bf[ni], acc[mi][ni], 0, 0, 0);
    }

    float bias[2];
#pragma unroll
    for (int ni = 0; ni < 2; ++ni) {
        int n = n0 + nwb + ni * 16 + ln;
        bias[ni] = bi[n] + bh[n];
    }
#pragma unroll
    for (int mi = 0; mi < 8; ++mi)
#pragma unroll
        for (int ni = 0; ni < 2; ++ni) {
            const int n = n0 + nwb + ni * 16 + ln;   // gate-major 0..511
            const int pos = ((n & 127) << 2) + (n >> 7);  // [j][gate]
#pragma unroll
            for (int rg = 0; rg < 4; ++rg) {
                const int m = mi * 16 + lq * 4 + rg;
                const size_t r = (size_t)(r0 + m);
                Gout[(r << 9) + pos] = f2bf(acc[mi][ni][rg] + bias[ni]);
            }
        }
}

// =====================================================================
// K2: LSTM recurrence, BOTH directions interleaved in one WG (R13).
// R12 analysis: step = 1371 cyc but busy work only ~550 (MFMA 258 from
// MfmaUtil, VALU ~300) -> ~800 cyc/step of exposed latency (barrier ->
// ds_read h -> MFMA wait -> exp/rcp chain -> f8enc -> ds_write -> barrier)
// with nothing to hide it: one serial chain per WG in lockstep barriers.
// Fix: fold the independent fwd+bwd chains of one batch into one WG.
// Per wave: 8 independent K=128 fp8 MFMAs (4/dir), two independent
// activation chains, two LDS h buffers, ONE shared barrier. Chain F's
// latencies hide under chain B's issue work and vice versa.
// Also: G repacked [t][b][j][gate] -> one dwordx2 load per dir per step
// (was 4 scalar ushort loads), hi-half bf16 unpack is a single AND.
// Grid: 64 WGs (one per batch), 512 threads.
// =====================================================================
__global__ __launch_bounds__(512, 2) void k_lstm(
    const unsigned char* __restrict__ whh8,
    const unsigned short* __restrict__ G_f, const unsigned short* __restrict__ G_b,
    unsigned short* __restrict__ h_f, unsigned short* __restrict__ h_b)
{
    const int tid = threadIdx.x;
    const int w = tid >> 6;
    const int lane = tid & 63;
    const int ln = lane & 15;
    const int quad = lane >> 4;
    const int b = blockIdx.x;           // batch (one per WG, both dirs)

    const int j = w * 16 + ln;          // this lane's h index (gate column)

    __shared__ __align__(16) unsigned char hls[2][2][128];  // [dir][parity][j], fp8 x16

    // ---- weights (B-frags): lane provides B[k=quad*32+i][n=ln] = W8[q*128+j][quad*32+i]
    const unsigned char* wp8 = whh8 + (size_t)quad * 32;
    const i8v wF0 = *(const i8v*)(wp8 + ((size_t)(0 * 128 + j) << 7));
    const i8v wF1 = *(const i8v*)(wp8 + ((size_t)(1 * 128 + j) << 7));
    const i8v wF2 = *(const i8v*)(wp8 + ((size_t)(2 * 128 + j) << 7));
    const i8v wF3 = *(const i8v*)(wp8 + ((size_t)(3 * 128 + j) << 7));
    const i8v wB0 = *(const i8v*)(wp8 + 65536 + ((size_t)(0 * 128 + j) << 7));
    const i8v wB1 = *(const i8v*)(wp8 + 65536 + ((size_t)(1 * 128 + j) << 7));
    const i8v wB2 = *(const i8v*)(wp8 + 65536 + ((size_t)(2 * 128 + j) << 7));
    const i8v wB3 = *(const i8v*)(wp8 + 65536 + ((size_t)(3 * 128 + j) << 7));

    // zero all 4 h buffers (2 dirs x 2 parity x 128 fp8 = 128 dwords); fp8 0x00 == 0.0
    if (tid < 128) ((unsigned*)hls)[tid] = 0u;
    float cF = 0.0f, cB = 0.0f;
    __syncthreads();

    // ---- G pipeline preload: slot u holds packed gates [i|f] [g|o] of step u ----
    uint2 gpF[4], gpB[4];
#pragma unroll
    for (int u = 0; u < 4; ++u) {
        gpF[u] = *(const uint2*)(G_f + (((size_t)u * Bn + b) << 9) + (j << 2));
        gpB[u] = *(const uint2*)(G_b + (((size_t)(Tn - 1 - u) * Bn + b) << 9) + (j << 2));
    }

    const float ds = 0.0009765625f;     // 1/(64*16) descale

    for (int blk = 0; blk < Tn / 4; ++blk) {
#pragma unroll
        for (int u = 0; u < 4; ++u) {
            const int s = blk * 4 + u;
            const int p = u & 1;          // h buffer parity (blk*4 is even)

            // consume slot u (loaded at step s-4; long since landed)
            const uint2 gFv = gpF[u];
            const uint2 gBv = gpB[u];

            // prefetch step s+4 into slot u (static index -> stays in regs)
            if (s + 4 < Tn) {
                gpF[u] = *(const uint2*)(G_f + (((size_t)(s + 4) * Bn + b) << 9) + (j << 2));
                gpB[u] = *(const uint2*)(G_b + (((size_t)(Tn - 5 - s) * Bn + b) << 9) + (j << 2));
            }

            // ---- A-frags: 32 fp8 of h per dir, k = quad*32 .. +32 (broadcast across ln)
            const i8v haF = *(const i8v*)&hls[0][p][quad * 32];
            const i8v haB = *(const i8v*)&hls[1][p][quad * 32];

            // ---- 8 INDEPENDENT K=128 fp8 MFMAs (4 per dir)
            const fl4 z = (fl4){0.f, 0.f, 0.f, 0.f};
            fl4 aF0 = __builtin_amdgcn_mfma_scale_f32_16x16x128_f8f6f4(
                          haF, wF0, z, 0, 0, 0, 0x7F7F7F7F, 0, 0x7F7F7F7F);
            fl4 aF1 = __builtin_amdgcn_mfma_scale_f32_16x16x128_f8f6f4(
                          haF, wF1, z, 0, 0, 0, 0x7F7F7F7F, 0, 0x7F7F7F7F);
            fl4 aF2 = __builtin_amdgcn_mfma_scale_f32_16x16x128_f8f6f4(
                          haF, wF2, z, 0, 0, 0, 0x7F7F7F7F, 0, 0x7F7F7F7F);
            fl4 aF3 = __builtin_amdgcn_mfma_scale_f32_16x16x128_f8f6f4(
                          haF, wF3, z, 0, 0, 0, 0x7F7F7F7F, 0, 0x7F7F7F7F);
            fl4 aB0 = __builtin_amdgcn_mfma_scale_f32_16x16x128_f8f6f4(
                          haB, wB0, z, 0, 0, 0, 0x7F7F7F7F, 0, 0x7F7F7F7F);
            fl4 aB1 = __builtin_amdgcn_mfma_scale_f32_16x16x128_f8f6f4(
                          haB, wB1, z, 0, 0, 0, 0x7F7F7F7F, 0, 0x7F7F7F7F);
            fl4 aB2 = __builtin_amdgcn_mfma_scale_f32_16x16x128_f8f6f4(
                          haB, wB2, z, 0, 0, 0, 0x7F7F7F7F, 0, 0x7F7F7F7F);
            fl4 aB3 = __builtin_amdgcn_mfma_scale_f32_16x16x128_f8f6f4(
                          haB, wB3, z, 0, 0, 0, 0x7F7F7F7F, 0, 0x7F7F7F7F);

            // ---- two independent activation chains (compiler interleaves) ----
            float hnF = lstm_cell(aF0[0], aF1[0], aF2[0], aF3[0], gFv.x, gFv.y, ds, cF);
            float hnB = lstm_cell(aB0[0], aB1[0], aB2[0], aB3[0], gBv.x, gBv.y, ds, cB);

            // ---- h writes (quad==0 lanes cover all 128 j): LDS fp8(x16) + global bf16
            if (quad == 0) {
                hls[0][1 - p][j] = f8enc(hnF * 16.0f);
                hls[1][1 - p][j] = f8enc(hnB * 16.0f);
                h_f[(((size_t)s * Bn + b) << 7) + j] = f2bf(hnF);
                h_b[(((size_t)(Tn - 1 - s) * Bn + b) << 7) + j] = f2bf(hnB);
            }

            barrier_lds_only();
        }
    }
}

// =====================================================================
// K3: feats (unchanged).
// =====================================================================
__global__ __launch_bounds__(256) void k_feats(
    const unsigned short* __restrict__ h_f, const unsigned short* __restrict__ h_b,
    const float* __restrict__ w_out, const float* __restrict__ b_out,
    float* __restrict__ feats)
{
    __shared__ float wl[256][12];
    __shared__ float bl[12];
    const int tid = threadIdx.x;
#pragma unroll
    for (int s = 0; s < 9; ++s) wl[tid][s] = w_out[s * 256 + tid];
#pragma unroll
    for (int s = 9; s < 12; ++s) wl[tid][s] = 0.0f;
    if (tid < 12) bl[tid] = (tid < 9) ? b_out[tid] : 0.0f;
    __syncthreads();

    const int r = blockIdx.x * 256 + tid;
    const unsigned short* hfr = h_f + (size_t)r * 128;
    const unsigned short* hbr = h_b + (size_t)r * 128;
    float acc[12];
#pragma unroll
    for (int k = 0; k < 12; ++k) acc[k] = bl[k];

    for (int ch = 0; ch < 32; ++ch) {
        const unsigned short* src = (ch < 16) ? (hfr + ch * 8) : (hbr + (ch - 16) * 8);
        uint4 hv = *(const uint4*)src;
        unsigned int hw0 = hv.x, hw1 = hv.y, hw2 = hv.z, hw3 = hv.w;
        const int jb = ch * 8;
#pragma unroll
        for (int q = 0; q < 8; ++q) {
            unsigned int word = (q < 2) ? hw0 : ((q < 4) ? hw1 : ((q < 6) ? hw2 : hw3));
            unsigned short hs = (q & 1) ? (unsigned short)(word >> 16) : (unsigned short)(word & 0xffff);
            float hf = bf2f(hs);
            const float* wrp = &wl[jb + q][0];
            float4 w0 = *(const float4*)(wrp);
            float4 w1 = *(const float4*)(wrp + 4);
            float4 w2 = *(const float4*)(wrp + 8);
            acc[0] += hf * w0.x; acc[1] += hf * w0.y; acc[2] += hf * w0.z; acc[3] += hf * w0.w;
            acc[4] += hf * w1.x; acc[5] += hf * w1.y; acc[6] += hf * w1.z; acc[7] += hf * w1.w;
            acc[8] += hf * w2.x; acc[9] += hf * w2.y; acc[10] += hf * w2.z; acc[11] += hf * w2.w;
        }
    }
    float* fr = feats + (size_t)r * 9;
#pragma unroll
    for (int k = 0; k < 9; ++k) fr[k] = acc[k];
}

// =====================================================================
// K4: Viterbi (unchanged).
// =====================================================================
__global__ __launch_bounds__(64) void k_viterbi(
    const float* __restrict__ feats, const float* __restrict__ trans,
    float* __restrict__ out)
{
    __shared__ __align__(16) unsigned char bp[1024 * 16];
    __shared__ float fl[1024 * 9];
    __shared__ float dl[12];
    __shared__ unsigned char pt[1024];

    const int b = blockIdx.x, tid = threadIdx.x;

    for (int i = tid; i < 9216; i += 64) {
        int t = i / 9;
        int n = i - t * 9;
        fl[i] = feats[((size_t)t * 64 + b) * 9 + n];
    }

    float tr[9];
    float trs = -3.0e38f;
    if (tid < 9) {
#pragma unroll
        for (int p = 0; p < 9; ++p) tr[p] = trans[tid * 9 + p];
        trs = trans[8 * 9 + tid];
    }
    if (tid < 12) dl[tid] = (tid == 7) ? 0.0f : NEGV;
    __syncthreads();

    if (tid < 9) {
        for (int t = 0; t < 1024; ++t) {
            float4 d0 = *(const float4*)&dl[0];
            float4 d1 = *(const float4*)&dl[4];
            float d8 = dl[8];
            float dv0 = d0.x, dv1 = d0.y, dv2 = d0.z, dv3 = d0.w;
            float dv4 = d1.x, dv5 = d1.y, dv6 = d1.z, dv7 = d1.w;
            float m = dv0 + tr[0]; int am = 0;
            float v;
            v = dv1 + tr[1]; if (v > m) { m = v; am = 1; }
            v = dv2 + tr[2]; if (v > m) { m = v; am = 2; }
            v = dv3 + tr[3]; if (v > m) { m = v; am = 3; }
            v = dv4 + tr[4]; if (v > m) { m = v; am = 4; }
            v = dv5 + tr[5]; if (v > m) { m = v; am = 5; }
            v = dv6 + tr[6]; if (v > m) { m = v; am = 6; }
            v = dv7 + tr[7]; if (v > m) { m = v; am = 7; }
            v = d8  + tr[8]; if (v > m) { m = v; am = 8; }
            float nd = m + fl[t * 9 + tid];
            dl[tid] = nd;
            bp[t * 16 + tid] = (unsigned char)am;
        }
    }
    float tv = (tid < 9) ? (dl[tid] + trs) : -3.0e38f;
    int bi = tid;
#pragma unroll
    for (int off = 8; off >= 1; off >>= 1) {
        float ov = __shfl_down(tv, off, 64);
        int oi = __shfl_down(bi, off, 64);
        if (ov > tv || (ov == tv && oi < bi)) { tv = ov; bi = oi; }
    }
    int best = __shfl(bi, 0, 64);
    if (tid == 0) out[b] = tv;

    if (tid == 0) {
        int tag = best;
        for (int t0 = 1023; t0 >= 0; t0 -= 8) {
            uint4 rows[8];
#pragma unroll
            for (int i = 0; i < 8; ++i) rows[i] = *(const uint4*)&bp[(t0 - i) * 16];
#pragma unroll
            for (int i = 0; i < 8; ++i) {
                pt[t0 - i] = (unsigned char)tag;
                uint4 rw = rows[i];
                unsigned int sel = (unsigned int)tag >> 2;
                unsigned int word = (sel == 0) ? rw.x : ((sel == 1) ? rw.y : rw.z);
                tag = (int)((word >> ((tag & 3) * 8)) & 0xffu);
            }
        }
    }
    for (int i = tid; i < 1024; i += 64) {
        out[64 + b * 1024 + i] = (float)pt[i];
    }
}

// =====================================================================
extern "C" void kernel_launch(void* const* d_in, const int* in_sizes, int n_in,
                              void* d_out, int out_size, void* d_ws, size_t ws_size,
                              hipStream_t stream) {
    const int*   sent   = (const int*)d_in[0];
    const float* embed  = (const float*)d_in[1];
    const float* w_ih_f = (const float*)d_in[2];
    const float* w_hh_f = (const float*)d_in[3];
    const float* b_ih_f = (const float*)d_in[4];
    const float* b_hh_f = (const float*)d_in[5];
    const float* w_ih_b = (const float*)d_in[6];
    const float* w_hh_b = (const float*)d_in[7];
    const float* b_ih_b = (const float*)d_in[8];
    const float* b_hh_b = (const float*)d_in[9];
    const float* w_out  = (const float*)d_in[10];
    const float* b_out  = (const float*)d_in[11];
    const float* trans  = (const float*)d_in[12];
    float* out = (float*)d_out;

    unsigned short* G_f = (unsigned short*)d_ws;
    unsigned short* G_b = G_f + (size_t)Tn * Bn * G4;
    unsigned short* h_f = G_b + (size_t)Tn * Bn * G4;
    unsigned short* h_b = h_f + (size_t)Tn * Bn * 128;
    float* feats = (float*)(h_b + (size_t)Tn * Bn * 128);
    unsigned char* whh8 = (unsigned char*)(feats + (size_t)Tn * Bn * 9);

    k_wcvt<<<512, 256, 0, stream>>>(w_hh_f, w_hh_b, whh8);
    k_inproj<<<dim3(512, 4, 2), 256, 0, stream>>>(sent, embed,
        w_ih_f, b_ih_f, b_hh_f, w_ih_b, b_ih_b, b_hh_b, G_f, G_b);
    k_lstm<<<dim3(64), 512, 0, stream>>>(whh8, G_f, G_b, h_f, h_b);
    k_feats<<<256, 256, 0, stream>>>(h_f, h_b, w_out, b_out, feats);
    k_viterbi<<<64, 64, 0, stream>>>(feats, trans, out);
}

// Round 3
// 895.602 us; speedup vs baseline: 1.6431x; 1.6431x over previous
//
#include <hip/hip_runtime.h>
#include <hip/hip_bf16.h>

#define Tn 1024
#define Bn 64
#define En 128
#define G4 512
#define NEGV -10000.0f

typedef short bh8 __attribute__((ext_vector_type(8)));
typedef float fl4 __attribute__((ext_vector_type(4)));
typedef int i8v __attribute__((ext_vector_type(8)));

// ---------- fast transcendental primitives ----------
#if __has_builtin(__builtin_amdgcn_exp2f)
#define EXP2(x) __builtin_amdgcn_exp2f(x)
#else
#define EXP2(x) exp2f(x)
#endif
#if __has_builtin(__builtin_amdgcn_rcpf)
#define RCP(x) __builtin_amdgcn_rcpf(x)
#else
#define RCP(x) (1.0f / (x))
#endif

#define LOG2E  1.4426950408889634f
#define LOG2E2 2.8853900817779268f

// ---------- bf16 helpers ----------
__device__ __forceinline__ float bf2f(unsigned short u) {
    unsigned int v = ((unsigned int)u) << 16;
    float f;
    __builtin_memcpy(&f, &v, 4);
    return f;
}
__device__ __forceinline__ unsigned short f2bf(float f) {
    unsigned int u;
    __builtin_memcpy(&u, &f, 4);
    u = (u + 0x7fffu + ((u >> 16) & 1u)) >> 16;
    return (unsigned short)u;
}
__device__ __forceinline__ float asf(unsigned int u) {
    float f;
    __builtin_memcpy(&f, &u, 4);
    return f;
}

// ---------- fp8 e4m3fn encode ----------
__device__ __forceinline__ unsigned char f8enc(float x) {
#if __has_builtin(__builtin_amdgcn_cvt_pk_fp8_f32)
    int pk = __builtin_amdgcn_cvt_pk_fp8_f32(x, 0.0f, 0, false);
    return (unsigned char)(pk & 0xff);
#else
    // manual OCP e4m3fn (RNE): max 448, min normal 2^-6, subnormal step 2^-9
    unsigned u;
    __builtin_memcpy(&u, &x, 4);
    unsigned s = (u >> 31) << 7;
    float a = fabsf(x);
    if (!(a > 0.0f)) return (unsigned char)s;
    if (a >= 464.0f) return (unsigned char)(s | 0x7E);
    if (a < 0.015625f) {
        int q = (int)rintf(a * 512.0f);
        return (unsigned char)(s | (unsigned)q);
    }
    int ex;
    (void)frexpf(a, &ex);
    int E = ex - 1;
    float t = ldexpf(a, -E);
    int m3 = (int)rintf((t - 1.0f) * 8.0f);
    if (m3 == 8) { m3 = 0; E += 1; }
    if (E > 8) return (unsigned char)(s | 0x7E);
    return (unsigned char)(s | ((unsigned)(E + 7) << 3) | (unsigned)m3);
#endif
}

// lgkm-only barrier: LDS visibility without draining vmcnt.
// imm 0xC07F = vmcnt(63) expcnt(7) lgkmcnt(0).
__device__ __forceinline__ void barrier_lds_only() {
    __builtin_amdgcn_s_waitcnt(0xC07F);
    __builtin_amdgcn_s_barrier();
}

// =====================================================================
// K0: one-time weight conversion whh (fp32 [512][128], both dirs) -> fp8 e4m3
// scaled by 64 (keeps w ~ N(0,0.01) in e4m3's normal range).
// =====================================================================
__global__ __launch_bounds__(256) void k_wcvt(
    const float* __restrict__ wf, const float* __restrict__ wb,
    unsigned char* __restrict__ o)
{
    const int i = blockIdx.x * 256 + threadIdx.x;   // 0 .. 131071
    const float v = (i < 65536) ? wf[i] : wb[i - 65536];
    o[i] = f8enc(v * 64.0f);
}

// =====================================================================
// K1: input projection via bf16 MFMA.
// G layout [t][b][j][gate] (4 ushorts contiguous per j) -> k_lstm fetches
// all 4 gate pre-acts with ONE dwordx2 load.
// R14: G stored PRE-SCALED by log2(e) (gates i,f,o) / 2*log2(e) (gate g)
// so k_lstm's sigmoid/tanh use raw v_exp (exp2) with no scaling multiply.
// =====================================================================
__global__ __launch_bounds__(256) void k_inproj(
    const int* __restrict__ sent, const float* __restrict__ embed,
    const float* __restrict__ w_ih_f, const float* __restrict__ b_ih_f, const float* __restrict__ b_hh_f,
    const float* __restrict__ w_ih_b, const float* __restrict__ b_ih_b, const float* __restrict__ b_hh_b,
    unsigned short* __restrict__ G_f, unsigned short* __restrict__ G_b)
{
    __shared__ unsigned short Asm[128][136];
    __shared__ unsigned short Bsm[128][136];
    const int tid = threadIdx.x;
    const int dir = blockIdx.z;
    const float* w_ih = dir ? w_ih_b : w_ih_f;
    const float* bi   = dir ? b_ih_b : b_ih_f;
    const float* bh   = dir ? b_hh_b : b_hh_f;
    unsigned short* Gout = dir ? G_b : G_f;

    const int mt = blockIdx.x, nt = blockIdx.y;
    const int r0 = mt * 128, n0 = nt * 128;

    const int srow = tid >> 1;
    const int ch = (tid & 1) * 64;
    {
        const int rg = r0 + srow;
        const int tt = rg >> 6, bb = rg & 63;
        const int tok = sent[bb * Tn + tt];
        const float* ar = embed + (size_t)tok * En + ch;
        const float* br = w_ih + (size_t)(n0 + srow) * En + ch;
#pragma unroll
        for (int i = 0; i < 64; i += 4) {
            float4 v = *(const float4*)(ar + i);
            *(unsigned*)&Asm[srow][ch + i]     = (unsigned)f2bf(v.x) | ((unsigned)f2bf(v.y) << 16);
            *(unsigned*)&Asm[srow][ch + i + 2] = (unsigned)f2bf(v.z) | ((unsigned)f2bf(v.w) << 16);
            float4 u = *(const float4*)(br + i);
            *(unsigned*)&Bsm[srow][ch + i]     = (unsigned)f2bf(u.x) | ((unsigned)f2bf(u.y) << 16);
            *(unsigned*)&Bsm[srow][ch + i + 2] = (unsigned)f2bf(u.z) | ((unsigned)f2bf(u.w) << 16);
        }
    }
    __syncthreads();

    const int w = tid >> 6, lane = tid & 63;
    const int ln = lane & 15, lq = lane >> 4;
    const int nwb = w * 32;

    fl4 acc[8][2];
#pragma unroll
    for (int mi = 0; mi < 8; ++mi)
#pragma unroll
        for (int ni = 0; ni < 2; ++ni) acc[mi][ni] = (fl4){0.f, 0.f, 0.f, 0.f};

#pragma unroll
    for (int kt = 0; kt < 4; ++kt) {
        const int kc = kt * 32 + lq * 8;
        bh8 a[8], bf[2];
#pragma unroll
        for (int mi = 0; mi < 8; ++mi) a[mi] = *(const bh8*)&Asm[mi * 16 + ln][kc];
#pragma unroll
        for (int ni = 0; ni < 2; ++ni) bf[ni] = *(const bh8*)&Bsm[nwb + ni * 16 + ln][kc];
#pragma unroll
        for (int mi = 0; mi < 8; ++mi)
#pragma unroll
            for (int ni = 0; ni < 2; ++ni)
                acc[mi][ni] = __builtin_amdgcn_mfma_f32_16x16x32_bf16(a[mi], bf[ni], acc[mi][ni], 0, 0, 0);
    }

    float bias[2], gsc[2];
#pragma unroll
    for (int ni = 0; ni < 2; ++ni) {
        int n = n0 + nwb + ni * 16 + ln;
        bias[ni] = bi[n] + bh[n];
        gsc[ni] = ((n >> 7) == 2) ? LOG2E2 : LOG2E;   // gate g gets 2*log2e
    }
#pragma unroll
    for (int mi = 0; mi < 8; ++mi)
#pragma unroll
        for (int ni = 0; ni < 2; ++ni) {
            const int n = n0 + nwb + ni * 16 + ln;          // gate-major 0..511
            const int pos = ((n & 127) << 2) + (n >> 7);    // [j][gate]
#pragma unroll
            for (int rg = 0; rg < 4; ++rg) {
                const int m = mi * 16 + lq * 4 + rg;
                const size_t r = (size_t)(r0 + m);
                Gout[(r << 9) + pos] = f2bf((acc[mi][ni][rg] + bias[ni]) * gsc[ni]);
            }
        }
}

// =====================================================================
// K2: LSTM recurrence — R12 structure restored (one (batch,dir) per WG,
// 128 WGs; per-step critical path of ONE chain is the wall time, and it
// is issue-bound on its CU, so per-CU work must stay minimal — R13's
// dual-dir interleave doubled per-CU issue and regressed 585->1008 us).
// Kept from R13: packed G [t][b][j][gate] (1 dwordx2/step, was 4 scalar
// loads). New: exp2-folded activations (G pre-scaled by log2e / 2log2e,
// per-gate descale), explicit v_rcp — ~4 fewer VALU + shorter dep chain.
// W: fp8 e4m3 x64. h: fp8 x16 in LDS, bf16 in global. 4 independent
// K=128 fp8 MFMAs/step. G: 4-slot register pipeline, lgkm-only barrier.
// =====================================================================
__global__ __launch_bounds__(512, 2) void k_lstm(
    const unsigned char* __restrict__ whh8,
    const unsigned short* __restrict__ G_f, const unsigned short* __restrict__ G_b,
    unsigned short* __restrict__ h_f, unsigned short* __restrict__ h_b)
{
    const int tid = threadIdx.x;
    const int w = tid >> 6;
    const int lane = tid & 63;
    const int ln = lane & 15;
    const int quad = lane >> 4;
    const int b = blockIdx.x;           // batch
    const int dir = blockIdx.y;
    const unsigned short* Gd = dir ? G_b : G_f;
    unsigned short* ho = dir ? h_b : h_f;

    const int j = w * 16 + ln;          // this lane's h index (gate column)

    __shared__ __align__(16) unsigned char hls8[2][128];   // fp8 h (x16), double-buffered

    // ---- weights (B-frags): lane provides B[k=quad*32+i][n=ln] = W8[q*128+j][quad*32+i]
    const unsigned char* wb8 = whh8 + (size_t)dir * 65536 + quad * 32;
    const i8v w0 = *(const i8v*)(wb8 + ((size_t)(0 * 128 + j) << 7));
    const i8v w1 = *(const i8v*)(wb8 + ((size_t)(1 * 128 + j) << 7));
    const i8v w2 = *(const i8v*)(wb8 + ((size_t)(2 * 128 + j) << 7));
    const i8v w3 = *(const i8v*)(wb8 + ((size_t)(3 * 128 + j) << 7));

    // zero both h buffers (2*128 fp8 = 64 dwords); fp8 0x00 == 0.0
    if (tid < 64) ((unsigned*)hls8)[tid] = 0u;
    float c = 0.0f;
    __syncthreads();

    // ---- G pipeline preload: slot u = packed gates [i|f] [g|o] of step u ----
    uint2 gp[4];
#pragma unroll
    for (int u = 0; u < 4; ++u) {
        const int tt = dir ? (Tn - 1 - u) : u;
        gp[u] = *(const uint2*)(Gd + (((size_t)tt * Bn + b) << 9) + (j << 2));
    }

    const float dsL  = 0.0009765625f * LOG2E;    // 1/(64*16) descale, log2e-folded
    const float ds2L = 0.0009765625f * LOG2E2;   // g-gate descale

    for (int blk = 0; blk < Tn / 4; ++blk) {
#pragma unroll
        for (int u = 0; u < 4; ++u) {
            const int s = blk * 4 + u;
            const int t = dir ? (Tn - 1 - s) : s;
            const int p = u & 1;          // h buffer parity (blk*4 is even)

            // consume slot u (loaded at step s-4)
            const uint2 gv = gp[u];

            // prefetch step s+4 into slot u (static index -> stays in regs)
            if (s + 4 < Tn) {
                const int tt = dir ? (Tn - 5 - s) : (s + 4);
                gp[u] = *(const uint2*)(Gd + (((size_t)tt * Bn + b) << 9) + (j << 2));
            }

            // ---- A-frag: 32 fp8 of h, k = quad*32 .. +32 (broadcast across ln)
            const i8v ha = *(const i8v*)&hls8[p][quad * 32];

            // ---- 4 INDEPENDENT K=128 fp8 MFMAs: aq = dot(h, W[q*128+j]) * 1024
            const fl4 z = (fl4){0.f, 0.f, 0.f, 0.f};
            fl4 a0 = __builtin_amdgcn_mfma_scale_f32_16x16x128_f8f6f4(
                         ha, w0, z, 0, 0, 0, 0x7F7F7F7F, 0, 0x7F7F7F7F);
            fl4 a1 = __builtin_amdgcn_mfma_scale_f32_16x16x128_f8f6f4(
                         ha, w1, z, 0, 0, 0, 0x7F7F7F7F, 0, 0x7F7F7F7F);
            fl4 a2 = __builtin_amdgcn_mfma_scale_f32_16x16x128_f8f6f4(
                         ha, w2, z, 0, 0, 0, 0x7F7F7F7F, 0, 0x7F7F7F7F);
            fl4 a3 = __builtin_amdgcn_mfma_scale_f32_16x16x128_f8f6f4(
                         ha, w3, z, 0, 0, 0, 0x7F7F7F7F, 0, 0x7F7F7F7F);

            // ---- activation (log2-domain pre-acts; hw exp2 + rcp) ----
            float pi = __builtin_fmaf(a0[0], dsL,  asf(gv.x << 16));
            float pf = __builtin_fmaf(a1[0], dsL,  asf(gv.x & 0xffff0000u));
            float pg = __builtin_fmaf(a2[0], ds2L, asf(gv.y << 16));
            float po = __builtin_fmaf(a3[0], dsL,  asf(gv.y & 0xffff0000u));
            float iv = RCP(1.0f + EXP2(-pi));
            float fv = RCP(1.0f + EXP2(-pf));
            float ov = RCP(1.0f + EXP2(-po));
            float gvv = 1.0f - 2.0f * RCP(1.0f + EXP2(pg));
            c = fv * c + iv * gvv;
            float th = 1.0f - 2.0f * RCP(1.0f + EXP2(c * LOG2E2));
            float hn = ov * th;

            // ---- h writes (quad==0 lanes cover all 128 j): LDS fp8(x16) + global bf16
            if (quad == 0) {
                hls8[1 - p][j] = f8enc(hn * 16.0f);
                ho[(((size_t)t * Bn + b) << 7) + j] = f2bf(hn);
            }

            barrier_lds_only();
        }
    }
}

// =====================================================================
// K3: feats (unchanged).
// =====================================================================
__global__ __launch_bounds__(256) void k_feats(
    const unsigned short* __restrict__ h_f, const unsigned short* __restrict__ h_b,
    const float* __restrict__ w_out, const float* __restrict__ b_out,
    float* __restrict__ feats)
{
    __shared__ float wl[256][12];
    __shared__ float bl[12];
    const int tid = threadIdx.x;
#pragma unroll
    for (int s = 0; s < 9; ++s) wl[tid][s] = w_out[s * 256 + tid];
#pragma unroll
    for (int s = 9; s < 12; ++s) wl[tid][s] = 0.0f;
    if (tid < 12) bl[tid] = (tid < 9) ? b_out[tid] : 0.0f;
    __syncthreads();

    const int r = blockIdx.x * 256 + tid;
    const unsigned short* hfr = h_f + (size_t)r * 128;
    const unsigned short* hbr = h_b + (size_t)r * 128;
    float acc[12];
#pragma unroll
    for (int k = 0; k < 12; ++k) acc[k] = bl[k];

    for (int ch = 0; ch < 32; ++ch) {
        const unsigned short* src = (ch < 16) ? (hfr + ch * 8) : (hbr + (ch - 16) * 8);
        uint4 hv = *(const uint4*)src;
        unsigned int hw0 = hv.x, hw1 = hv.y, hw2 = hv.z, hw3 = hv.w;
        const int jb = ch * 8;
#pragma unroll
        for (int q = 0; q < 8; ++q) {
            unsigned int word = (q < 2) ? hw0 : ((q < 4) ? hw1 : ((q < 6) ? hw2 : hw3));
            unsigned short hs = (q & 1) ? (unsigned short)(word >> 16) : (unsigned short)(word & 0xffff);
            float hf = bf2f(hs);
            const float* wrp = &wl[jb + q][0];
            float4 w0 = *(const float4*)(wrp);
            float4 w1 = *(const float4*)(wrp + 4);
            float4 w2 = *(const float4*)(wrp + 8);
            acc[0] += hf * w0.x; acc[1] += hf * w0.y; acc[2] += hf * w0.z; acc[3] += hf * w0.w;
            acc[4] += hf * w1.x; acc[5] += hf * w1.y; acc[6] += hf * w1.z; acc[7] += hf * w1.w;
            acc[8] += hf * w2.x; acc[9] += hf * w2.y; acc[10] += hf * w2.z; acc[11] += hf * w2.w;
        }
    }
    float* fr = feats + (size_t)r * 9;
#pragma unroll
    for (int k = 0; k < 9; ++k) fr[k] = acc[k];
}

// =====================================================================
// K4: Viterbi — R14 rewrite: delta recursion fully in registers.
// Old version round-tripped dl[] through LDS every one of 1024 serial
// steps (~120 cyc read latency each). Now lane n (n<9) keeps delta_n in
// a register; the 9 previous deltas are gathered with __shfl (in-register
// cross-lane, no barrier needed within a wave); feats prefetched from LDS
// one step ahead. Same strict-> first-max scan => identical tie-breaking.
// =====================================================================
__global__ __launch_bounds__(64) void k_viterbi(
    const float* __restrict__ feats, const float* __restrict__ trans,
    float* __restrict__ out)
{
    __shared__ __align__(16) unsigned char bp[1024 * 16];
    __shared__ float fl[1024 * 9];
    __shared__ unsigned char pt[1024];

    const int b = blockIdx.x, tid = threadIdx.x;

    for (int i = tid; i < 9216; i += 64) {
        int t = i / 9;
        int n = i - t * 9;
        fl[i] = feats[((size_t)t * 64 + b) * 9 + n];
    }

    const int n9 = (tid < 9) ? tid : 8;   // clamp so inactive lanes load valid addrs
    float trn[9];
#pragma unroll
    for (int p = 0; p < 9; ++p) trn[p] = trans[n9 * 9 + p];
    float trs = (tid < 9) ? trans[8 * 9 + tid] : -3.0e38f;

    float delta = (n9 == 7) ? 0.0f : NEGV;   // START=7
    __syncthreads();

    float fnext = fl[n9];                     // feats for t=0
    for (int t = 0; t < 1024; ++t) {
        // gather all 9 previous deltas (uniform lane indices -> in-register)
        float d0 = __shfl(delta, 0, 64);
        float d1 = __shfl(delta, 1, 64);
        float d2 = __shfl(delta, 2, 64);
        float d3 = __shfl(delta, 3, 64);
        float d4 = __shfl(delta, 4, 64);
        float d5 = __shfl(delta, 5, 64);
        float d6 = __shfl(delta, 6, 64);
        float d7 = __shfl(delta, 7, 64);
        float d8 = __shfl(delta, 8, 64);
        float fhere = fnext;
        if (t < 1023) fnext = fl[(t + 1) * 9 + n9];   // prefetch next step

        float m = d0 + trn[0]; int am = 0;
        float v;
        v = d1 + trn[1]; if (v > m) { m = v; am = 1; }
        v = d2 + trn[2]; if (v > m) { m = v; am = 2; }
        v = d3 + trn[3]; if (v > m) { m = v; am = 3; }
        v = d4 + trn[4]; if (v > m) { m = v; am = 4; }
        v = d5 + trn[5]; if (v > m) { m = v; am = 5; }
        v = d6 + trn[6]; if (v > m) { m = v; am = 6; }
        v = d7 + trn[7]; if (v > m) { m = v; am = 7; }
        v = d8 + trn[8]; if (v > m) { m = v; am = 8; }
        delta = m + fhere;
        if (tid < 9) bp[t * 16 + tid] = (unsigned char)am;
    }

    float tv = (tid < 9) ? (delta + trs) : -3.0e38f;
    int bi = tid;
#pragma unroll
    for (int off = 8; off >= 1; off >>= 1) {
        float ov = __shfl_down(tv, off, 64);
        int oi = __shfl_down(bi, off, 64);
        if (ov > tv || (ov == tv && oi < bi)) { tv = ov; bi = oi; }
    }
    int best = __shfl(bi, 0, 64);
    if (tid == 0) out[b] = tv;

    if (tid == 0) {
        int tag = best;
        for (int t0 = 1023; t0 >= 0; t0 -= 8) {
            uint4 rows[8];
#pragma unroll
            for (int i = 0; i < 8; ++i) rows[i] = *(const uint4*)&bp[(t0 - i) * 16];
#pragma unroll
            for (int i = 0; i < 8; ++i) {
                pt[t0 - i] = (unsigned char)tag;
                uint4 rw = rows[i];
                unsigned int sel = (unsigned int)tag >> 2;
                unsigned int word = (sel == 0) ? rw.x : ((sel == 1) ? rw.y : rw.z);
                tag = (int)((word >> ((tag & 3) * 8)) & 0xffu);
            }
        }
    }
    for (int i = tid; i < 1024; i += 64) {
        out[64 + b * 1024 + i] = (float)pt[i];
    }
}

// =====================================================================
extern "C" void kernel_launch(void* const* d_in, const int* in_sizes, int n_in,
                              void* d_out, int out_size, void* d_ws, size_t ws_size,
                              hipStream_t stream) {
    const int*   sent   = (const int*)d_in[0];
    const float* embed  = (const float*)d_in[1];
    const float* w_ih_f = (const float*)d_in[2];
    const float* w_hh_f = (const float*)d_in[3];
    const float* b_ih_f = (const float*)d_in[4];
    const float* b_hh_f = (const float*)d_in[5];
    const float* w_ih_b = (const float*)d_in[6];
    const float* w_hh_b = (const float*)d_in[7];
    const float* b_ih_b = (const float*)d_in[8];
    const float* b_hh_b = (const float*)d_in[9];
    const float* w_out  = (const float*)d_in[10];
    const float* b_out  = (const float*)d_in[11];
    const float* trans  = (const float*)d_in[12];
    float* out = (float*)d_out;

    unsigned short* G_f = (unsigned short*)d_ws;
    unsigned short* G_b = G_f + (size_t)Tn * Bn * G4;
    unsigned short* h_f = G_b + (size_t)Tn * Bn * G4;
    unsigned short* h_b = h_f + (size_t)Tn * Bn * 128;
    float* feats = (float*)(h_b + (size_t)Tn * Bn * 128);
    unsigned char* whh8 = (unsigned char*)(feats + (size_t)Tn * Bn * 9);

    k_wcvt<<<512, 256, 0, stream>>>(w_hh_f, w_hh_b, whh8);
    k_inproj<<<dim3(512, 4, 2), 256, 0, stream>>>(sent, embed,
        w_ih_f, b_ih_f, b_hh_f, w_ih_b, b_ih_b, b_hh_b, G_f, G_b);
    k_lstm<<<dim3(64, 2), 512, 0, stream>>>(whh8, G_f, G_b, h_f, h_b);
    k_feats<<<256, 256, 0, stream>>>(h_f, h_b, w_out, b_out, feats);
    k_viterbi<<<64, 64, 0, stream>>>(feats, trans, out);
}

// Round 4
// 815.839 us; speedup vs baseline: 1.8037x; 1.0978x over previous
//
#include <hip/hip_runtime.h>
#include <hip/hip_bf16.h>

#define Tn 1024
#define Bn 64
#define En 128
#define G4 512
#define NEGV -10000.0f

typedef short bh8 __attribute__((ext_vector_type(8)));
typedef float fl4 __attribute__((ext_vector_type(4)));
typedef int i8v __attribute__((ext_vector_type(8)));

// ---------- fast transcendental primitives ----------
#if __has_builtin(__builtin_amdgcn_exp2f)
#define EXP2(x) __builtin_amdgcn_exp2f(x)
#else
#define EXP2(x) exp2f(x)
#endif
#if __has_builtin(__builtin_amdgcn_rcpf)
#define RCP(x) __builtin_amdgcn_rcpf(x)
#else
#define RCP(x) (1.0f / (x))
#endif

#define LOG2E  1.4426950408889634f
#define LOG2E2 2.8853900817779268f

// ---------- bf16 helpers ----------
__device__ __forceinline__ float bf2f(unsigned short u) {
    unsigned int v = ((unsigned int)u) << 16;
    float f;
    __builtin_memcpy(&f, &v, 4);
    return f;
}
__device__ __forceinline__ unsigned short f2bf(float f) {
    unsigned int u;
    __builtin_memcpy(&u, &f, 4);
    u = (u + 0x7fffu + ((u >> 16) & 1u)) >> 16;
    return (unsigned short)u;
}
__device__ __forceinline__ float asf(unsigned int u) {
    float f;
    __builtin_memcpy(&f, &u, 4);
    return f;
}
__device__ __forceinline__ float i2f(int u) {
    float f;
    __builtin_memcpy(&f, &u, 4);
    return f;
}
__device__ __forceinline__ int f2i(float f) {
    int u;
    __builtin_memcpy(&u, &f, 4);
    return u;
}

// ---------- fp8 e4m3fn encode ----------
__device__ __forceinline__ unsigned char f8enc(float x) {
#if __has_builtin(__builtin_amdgcn_cvt_pk_fp8_f32)
    int pk = __builtin_amdgcn_cvt_pk_fp8_f32(x, 0.0f, 0, false);
    return (unsigned char)(pk & 0xff);
#else
    // manual OCP e4m3fn (RNE): max 448, min normal 2^-6, subnormal step 2^-9
    unsigned u;
    __builtin_memcpy(&u, &x, 4);
    unsigned s = (u >> 31) << 7;
    float a = fabsf(x);
    if (!(a > 0.0f)) return (unsigned char)s;
    if (a >= 464.0f) return (unsigned char)(s | 0x7E);
    if (a < 0.015625f) {
        int q = (int)rintf(a * 512.0f);
        return (unsigned char)(s | (unsigned)q);
    }
    int ex;
    (void)frexpf(a, &ex);
    int E = ex - 1;
    float t = ldexpf(a, -E);
    int m3 = (int)rintf((t - 1.0f) * 8.0f);
    if (m3 == 8) { m3 = 0; E += 1; }
    if (E > 8) return (unsigned char)(s | 0x7E);
    return (unsigned char)(s | ((unsigned)(E + 7) << 3) | (unsigned)m3);
#endif
}

// lgkm-only barrier: LDS visibility without draining vmcnt.
// imm 0xC07F = vmcnt(63) expcnt(7) lgkmcnt(0).
__device__ __forceinline__ void barrier_lds_only() {
    __builtin_amdgcn_s_waitcnt(0xC07F);
    __builtin_amdgcn_s_barrier();
}

// =====================================================================
// K0: one-time weight conversion whh (fp32 [512][128], both dirs) -> fp8 e4m3
// scaled by 64 (keeps w ~ N(0,0.01) in e4m3's normal range).
// =====================================================================
__global__ __launch_bounds__(256) void k_wcvt(
    const float* __restrict__ wf, const float* __restrict__ wb,
    unsigned char* __restrict__ o)
{
    const int i = blockIdx.x * 256 + threadIdx.x;   // 0 .. 131071
    const float v = (i < 65536) ? wf[i] : wb[i - 65536];
    o[i] = f8enc(v * 64.0f);
}

// =====================================================================
// K1: input projection via bf16 MFMA.
// R15: weight rows are consumed PRE-PERMUTED so the N dimension directly
// enumerates the packed [j][gate] order (norig = (n&3)*128 + (n>>2)).
// Epilogue stores are then contiguous across the 16 ln-lanes (32B runs)
// instead of 2B stores at stride 8B (4 partial writers per 64B line).
// G values are bit-identical to R14 (same math, same final location).
// G stored pre-scaled by log2e (i,f,o) / 2*log2e (g) for exp2 activations.
// =====================================================================
__global__ __launch_bounds__(256) void k_inproj(
    const int* __restrict__ sent, const float* __restrict__ embed,
    const float* __restrict__ w_ih_f, const float* __restrict__ b_ih_f, const float* __restrict__ b_hh_f,
    const float* __restrict__ w_ih_b, const float* __restrict__ b_ih_b, const float* __restrict__ b_hh_b,
    unsigned short* __restrict__ G_f, unsigned short* __restrict__ G_b)
{
    __shared__ unsigned short Asm[128][136];
    __shared__ unsigned short Bsm[128][136];
    const int tid = threadIdx.x;
    const int dir = blockIdx.z;
    const float* w_ih = dir ? w_ih_b : w_ih_f;
    const float* bi   = dir ? b_ih_b : b_ih_f;
    const float* bh   = dir ? b_hh_b : b_hh_f;
    unsigned short* Gout = dir ? G_b : G_f;

    const int mt = blockIdx.x, nt = blockIdx.y;
    const int r0 = mt * 128, n0 = nt * 128;

    const int srow = tid >> 1;
    const int ch = (tid & 1) * 64;
    {
        const int rg = r0 + srow;
        const int tt = rg >> 6, bb = rg & 63;
        const int tok = sent[bb * Tn + tt];
        const int np = n0 + srow;                          // packed row index
        const int norig = ((np & 3) << 7) + (np >> 2);     // original w_ih row
        const float* ar = embed + (size_t)tok * En + ch;
        const float* br = w_ih + (size_t)norig * En + ch;
#pragma unroll
        for (int i = 0; i < 64; i += 4) {
            float4 v = *(const float4*)(ar + i);
            *(unsigned*)&Asm[srow][ch + i]     = (unsigned)f2bf(v.x) | ((unsigned)f2bf(v.y) << 16);
            *(unsigned*)&Asm[srow][ch + i + 2] = (unsigned)f2bf(v.z) | ((unsigned)f2bf(v.w) << 16);
            float4 u = *(const float4*)(br + i);
            *(unsigned*)&Bsm[srow][ch + i]     = (unsigned)f2bf(u.x) | ((unsigned)f2bf(u.y) << 16);
            *(unsigned*)&Bsm[srow][ch + i + 2] = (unsigned)f2bf(u.z) | ((unsigned)f2bf(u.w) << 16);
        }
    }
    __syncthreads();

    const int w = tid >> 6, lane = tid & 63;
    const int ln = lane & 15, lq = lane >> 4;
    const int nwb = w * 32;

    fl4 acc[8][2];
#pragma unroll
    for (int mi = 0; mi < 8; ++mi)
#pragma unroll
        for (int ni = 0; ni < 2; ++ni) acc[mi][ni] = (fl4){0.f, 0.f, 0.f, 0.f};

#pragma unroll
    for (int kt = 0; kt < 4; ++kt) {
        const int kc = kt * 32 + lq * 8;
        bh8 a[8], bf[2];
#pragma unroll
        for (int mi = 0; mi < 8; ++mi) a[mi] = *(const bh8*)&Asm[mi * 16 + ln][kc];
#pragma unroll
        for (int ni = 0; ni < 2; ++ni) bf[ni] = *(const bh8*)&Bsm[nwb + ni * 16 + ln][kc];
#pragma unroll
        for (int mi = 0; mi < 8; ++mi)
#pragma unroll
            for (int ni = 0; ni < 2; ++ni)
                acc[mi][ni] = __builtin_amdgcn_mfma_f32_16x16x32_bf16(a[mi], bf[ni], acc[mi][ni], 0, 0, 0);
    }

    float bias[2], gsc[2];
#pragma unroll
    for (int ni = 0; ni < 2; ++ni) {
        const int np = n0 + nwb + ni * 16 + ln;            // packed index j*4+gate
        const int norig = ((np & 3) << 7) + (np >> 2);
        bias[ni] = bi[norig] + bh[norig];
        gsc[ni] = ((np & 3) == 2) ? LOG2E2 : LOG2E;        // gate g gets 2*log2e
    }
#pragma unroll
    for (int mi = 0; mi < 8; ++mi)
#pragma unroll
        for (int ni = 0; ni < 2; ++ni) {
            const int np = n0 + nwb + ni * 16 + ln;        // store position directly
#pragma unroll
            for (int rg = 0; rg < 4; ++rg) {
                const int m = mi * 16 + lq * 4 + rg;
                const size_t r = (size_t)(r0 + m);
                Gout[(r << 9) + np] = f2bf((acc[mi][ni][rg] + bias[ni]) * gsc[ni]);
            }
        }
}

// =====================================================================
// K2: LSTM recurrence (R12 structure: one (batch,dir) per WG, 128 WGs).
// R15: quad-specialized activations. R14 counters: per active CU,
// VALU issue ~445 cyc/SIMD/step of which ~160 is 10 redundant TRANS
// (every quad computed all 4 gates). Now quad q computes only gate q's
// t = rcp(1+exp2(+-p)) (sign/scale folded into lane constants, bf16-G
// negation = sign-bit XOR, bit-identical math), then 4 ds_bpermute
// (in-register wave crossbar, no barrier) gather {iv,fv,tg,ov} to all
// lanes. TRANS/wave: 10 -> 4 (own gate + tanh(c)).
// W: fp8 e4m3 x64. h: fp8 x16 in LDS, bf16 in global. 4 independent
// K=128 fp8 MFMAs/step. G: 4-slot register pipeline, lgkm-only barrier.
// =====================================================================
__global__ __launch_bounds__(512, 2) void k_lstm(
    const unsigned char* __restrict__ whh8,
    const unsigned short* __restrict__ G_f, const unsigned short* __restrict__ G_b,
    unsigned short* __restrict__ h_f, unsigned short* __restrict__ h_b)
{
    const int tid = threadIdx.x;
    const int w = tid >> 6;
    const int lane = tid & 63;
    const int ln = lane & 15;
    const int quad = lane >> 4;
    const int b = blockIdx.x;           // batch
    const int dir = blockIdx.y;
    const unsigned short* Gd = dir ? G_b : G_f;
    unsigned short* ho = dir ? h_b : h_f;

    const int j = w * 16 + ln;          // this lane's h index (gate column)

    __shared__ __align__(16) unsigned char hls8[2][128];   // fp8 h (x16), double-buffered

    // ---- weights (B-frags): lane provides B[k=quad*32+i][n=ln] = W8[q*128+j][quad*32+i]
    const unsigned char* wb8 = whh8 + (size_t)dir * 65536 + quad * 32;
    const i8v w0 = *(const i8v*)(wb8 + ((size_t)(0 * 128 + j) << 7));
    const i8v w1 = *(const i8v*)(wb8 + ((size_t)(1 * 128 + j) << 7));
    const i8v w2 = *(const i8v*)(wb8 + ((size_t)(2 * 128 + j) << 7));
    const i8v w3 = *(const i8v*)(wb8 + ((size_t)(3 * 128 + j) << 7));

    // zero both h buffers (2*128 fp8 = 64 dwords); fp8 0x00 == 0.0
    if (tid < 64) ((unsigned*)hls8)[tid] = 0u;
    float c = 0.0f;
    __syncthreads();

    // ---- G pipeline preload: slot u = packed gates [i|f] [g|o] of step u ----
    uint2 gp[4];
#pragma unroll
    for (int u = 0; u < 4; ++u) {
        const int tt = dir ? (Tn - 1 - u) : u;
        gp[u] = *(const uint2*)(Gd + (((size_t)tt * Bn + b) << 9) + (j << 2));
    }

    const float dsL  = 0.0009765625f * LOG2E;    // 1/(64*16) descale, log2e-folded
    const float ds2L = 0.0009765625f * LOG2E2;   // g-gate descale

    // ---- lane-constant activation params (quad q owns gate q) ----
    // q in {0,1,3}: p = -(a*dsL + g)  -> t = sigmoid(pre)
    // q == 2     : p = +(a*ds2L + g) -> t = 1/(1+e2^pg), tanh = 1-2t
    const float cds = (quad == 2) ? ds2L : -dsL;
    const unsigned gsign = (quad == 2) ? 0u : 0x80000000u;
    const int gshift = (quad & 1) ? 0 : 16;
    const int bp0 = (0 * 16 + ln) << 2;     // bpermute byte addrs (lane*4)
    const int bp1 = (1 * 16 + ln) << 2;
    const int bp2 = (2 * 16 + ln) << 2;
    const int bp3 = (3 * 16 + ln) << 2;

    for (int blk = 0; blk < Tn / 4; ++blk) {
#pragma unroll
        for (int u = 0; u < 4; ++u) {
            const int s = blk * 4 + u;
            const int t = dir ? (Tn - 1 - s) : s;
            const int p = u & 1;          // h buffer parity (blk*4 is even)

            // consume slot u (loaded at step s-4)
            const uint2 gv = gp[u];

            // prefetch step s+4 into slot u (static index -> stays in regs)
            if (s + 4 < Tn) {
                const int tt = dir ? (Tn - 5 - s) : (s + 4);
                gp[u] = *(const uint2*)(Gd + (((size_t)tt * Bn + b) << 9) + (j << 2));
            }

            // ---- A-frag: 32 fp8 of h, k = quad*32 .. +32 (broadcast across ln)
            const i8v ha = *(const i8v*)&hls8[p][quad * 32];

            // ---- 4 INDEPENDENT K=128 fp8 MFMAs: aq = dot(h, W[q*128+j]) * 1024
            const fl4 z = (fl4){0.f, 0.f, 0.f, 0.f};
            fl4 a0 = __builtin_amdgcn_mfma_scale_f32_16x16x128_f8f6f4(
                         ha, w0, z, 0, 0, 0, 0x7F7F7F7F, 0, 0x7F7F7F7F);
            fl4 a1 = __builtin_amdgcn_mfma_scale_f32_16x16x128_f8f6f4(
                         ha, w1, z, 0, 0, 0, 0x7F7F7F7F, 0, 0x7F7F7F7F);
            fl4 a2 = __builtin_amdgcn_mfma_scale_f32_16x16x128_f8f6f4(
                         ha, w2, z, 0, 0, 0, 0x7F7F7F7F, 0, 0x7F7F7F7F);
            fl4 a3 = __builtin_amdgcn_mfma_scale_f32_16x16x128_f8f6f4(
                         ha, w3, z, 0, 0, 0, 0x7F7F7F7F, 0, 0x7F7F7F7F);

            // ---- quad-specialized activation: own gate only ----
            float a01 = (quad & 1) ? a1[0] : a0[0];
            float a23 = (quad & 1) ? a3[0] : a2[0];
            float aown = (quad & 2) ? a23 : a01;
            unsigned wsel = (quad & 2) ? gv.y : gv.x;
            unsigned gb = ((wsel << gshift) & 0xffff0000u) ^ gsign;
            float pre = __builtin_fmaf(aown, cds, asf(gb));
            float tq = RCP(1.0f + EXP2(pre));
            // gather all four gate results to every lane (wave crossbar)
            int tqi = f2i(tq);
            float iv = i2f(__builtin_amdgcn_ds_bpermute(bp0, tqi));
            float fv = i2f(__builtin_amdgcn_ds_bpermute(bp1, tqi));
            float tg = i2f(__builtin_amdgcn_ds_bpermute(bp2, tqi));
            float ov = i2f(__builtin_amdgcn_ds_bpermute(bp3, tqi));
            float gvv = __builtin_fmaf(-2.0f, tg, 1.0f);
            c = __builtin_fmaf(fv, c, iv * gvv);
            float r2 = RCP(1.0f + EXP2(c * LOG2E2));
            float hn = ov * __builtin_fmaf(-2.0f, r2, 1.0f);

            // ---- h writes (quad==0 lanes cover all 128 j): LDS fp8(x16) + global bf16
            if (quad == 0) {
                hls8[1 - p][j] = f8enc(hn * 16.0f);
                ho[(((size_t)t * Bn + b) << 7) + j] = f2bf(hn);
            }

            barrier_lds_only();
        }
    }
}

// =====================================================================
// K3: feats (unchanged).
// =====================================================================
__global__ __launch_bounds__(256) void k_feats(
    const unsigned short* __restrict__ h_f, const unsigned short* __restrict__ h_b,
    const float* __restrict__ w_out, const float* __restrict__ b_out,
    float* __restrict__ feats)
{
    __shared__ float wl[256][12];
    __shared__ float bl[12];
    const int tid = threadIdx.x;
#pragma unroll
    for (int s = 0; s < 9; ++s) wl[tid][s] = w_out[s * 256 + tid];
#pragma unroll
    for (int s = 9; s < 12; ++s) wl[tid][s] = 0.0f;
    if (tid < 12) bl[tid] = (tid < 9) ? b_out[tid] : 0.0f;
    __syncthreads();

    const int r = blockIdx.x * 256 + tid;
    const unsigned short* hfr = h_f + (size_t)r * 128;
    const unsigned short* hbr = h_b + (size_t)r * 128;
    float acc[12];
#pragma unroll
    for (int k = 0; k < 12; ++k) acc[k] = bl[k];

    for (int ch = 0; ch < 32; ++ch) {
        const unsigned short* src = (ch < 16) ? (hfr + ch * 8) : (hbr + (ch - 16) * 8);
        uint4 hv = *(const uint4*)src;
        unsigned int hw0 = hv.x, hw1 = hv.y, hw2 = hv.z, hw3 = hv.w;
        const int jb = ch * 8;
#pragma unroll
        for (int q = 0; q < 8; ++q) {
            unsigned int word = (q < 2) ? hw0 : ((q < 4) ? hw1 : ((q < 6) ? hw2 : hw3));
            unsigned short hs = (q & 1) ? (unsigned short)(word >> 16) : (unsigned short)(word & 0xffff);
            float hf = bf2f(hs);
            const float* wrp = &wl[jb + q][0];
            float4 w0 = *(const float4*)(wrp);
            float4 w1 = *(const float4*)(wrp + 4);
            float4 w2 = *(const float4*)(wrp + 8);
            acc[0] += hf * w0.x; acc[1] += hf * w0.y; acc[2] += hf * w0.z; acc[3] += hf * w0.w;
            acc[4] += hf * w1.x; acc[5] += hf * w1.y; acc[6] += hf * w1.z; acc[7] += hf * w1.w;
            acc[8] += hf * w2.x; acc[9] += hf * w2.y; acc[10] += hf * w2.z; acc[11] += hf * w2.w;
        }
    }
    float* fr = feats + (size_t)r * 9;
#pragma unroll
    for (int k = 0; k < 9; ++k) fr[k] = acc[k];
}

// =====================================================================
// K4: Viterbi (R14 register/shfl version, unchanged).
// =====================================================================
__global__ __launch_bounds__(64) void k_viterbi(
    const float* __restrict__ feats, const float* __restrict__ trans,
    float* __restrict__ out)
{
    __shared__ __align__(16) unsigned char bp[1024 * 16];
    __shared__ float fl[1024 * 9];
    __shared__ unsigned char pt[1024];

    const int b = blockIdx.x, tid = threadIdx.x;

    for (int i = tid; i < 9216; i += 64) {
        int t = i / 9;
        int n = i - t * 9;
        fl[i] = feats[((size_t)t * 64 + b) * 9 + n];
    }

    const int n9 = (tid < 9) ? tid : 8;   // clamp so inactive lanes load valid addrs
    float trn[9];
#pragma unroll
    for (int p = 0; p < 9; ++p) trn[p] = trans[n9 * 9 + p];
    float trs = (tid < 9) ? trans[8 * 9 + tid] : -3.0e38f;

    float delta = (n9 == 7) ? 0.0f : NEGV;   // START=7
    __syncthreads();

    float fnext = fl[n9];                     // feats for t=0
    for (int t = 0; t < 1024; ++t) {
        // gather all 9 previous deltas (uniform lane indices -> in-register)
        float d0 = __shfl(delta, 0, 64);
        float d1 = __shfl(delta, 1, 64);
        float d2 = __shfl(delta, 2, 64);
        float d3 = __shfl(delta, 3, 64);
        float d4 = __shfl(delta, 4, 64);
        float d5 = __shfl(delta, 5, 64);
        float d6 = __shfl(delta, 6, 64);
        float d7 = __shfl(delta, 7, 64);
        float d8 = __shfl(delta, 8, 64);
        float fhere = fnext;
        if (t < 1023) fnext = fl[(t + 1) * 9 + n9];   // prefetch next step

        float m = d0 + trn[0]; int am = 0;
        float v;
        v = d1 + trn[1]; if (v > m) { m = v; am = 1; }
        v = d2 + trn[2]; if (v > m) { m = v; am = 2; }
        v = d3 + trn[3]; if (v > m) { m = v; am = 3; }
        v = d4 + trn[4]; if (v > m) { m = v; am = 4; }
        v = d5 + trn[5]; if (v > m) { m = v; am = 5; }
        v = d6 + trn[6]; if (v > m) { m = v; am = 6; }
        v = d7 + trn[7]; if (v > m) { m = v; am = 7; }
        v = d8 + trn[8]; if (v > m) { m = v; am = 8; }
        delta = m + fhere;
        if (tid < 9) bp[t * 16 + tid] = (unsigned char)am;
    }

    float tv = (tid < 9) ? (delta + trs) : -3.0e38f;
    int bi = tid;
#pragma unroll
    for (int off = 8; off >= 1; off >>= 1) {
        float ov = __shfl_down(tv, off, 64);
        int oi = __shfl_down(bi, off, 64);
        if (ov > tv || (ov == tv && oi < bi)) { tv = ov; bi = oi; }
    }
    int best = __shfl(bi, 0, 64);
    if (tid == 0) out[b] = tv;

    if (tid == 0) {
        int tag = best;
        for (int t0 = 1023; t0 >= 0; t0 -= 8) {
            uint4 rows[8];
#pragma unroll
            for (int i = 0; i < 8; ++i) rows[i] = *(const uint4*)&bp[(t0 - i) * 16];
#pragma unroll
            for (int i = 0; i < 8; ++i) {
                pt[t0 - i] = (unsigned char)tag;
                uint4 rw = rows[i];
                unsigned int sel = (unsigned int)tag >> 2;
                unsigned int word = (sel == 0) ? rw.x : ((sel == 1) ? rw.y : rw.z);
                tag = (int)((word >> ((tag & 3) * 8)) & 0xffu);
            }
        }
    }
    for (int i = tid; i < 1024; i += 64) {
        out[64 + b * 1024 + i] = (float)pt[i];
    }
}

// =====================================================================
extern "C" void kernel_launch(void* const* d_in, const int* in_sizes, int n_in,
                              void* d_out, int out_size, void* d_ws, size_t ws_size,
                              hipStream_t stream) {
    const int*   sent   = (const int*)d_in[0];
    const float* embed  = (const float*)d_in[1];
    const float* w_ih_f = (const float*)d_in[2];
    const float* w_hh_f = (const float*)d_in[3];
    const float* b_ih_f = (const float*)d_in[4];
    const float* b_hh_f = (const float*)d_in[5];
    const float* w_ih_b = (const float*)d_in[6];
    const float* w_hh_b = (const float*)d_in[7];
    const float* b_ih_b = (const float*)d_in[8];
    const float* b_hh_b = (const float*)d_in[9];
    const float* w_out  = (const float*)d_in[10];
    const float* b_out  = (const float*)d_in[11];
    const float* trans  = (const float*)d_in[12];
    float* out = (float*)d_out;

    unsigned short* G_f = (unsigned short*)d_ws;
    unsigned short* G_b = G_f + (size_t)Tn * Bn * G4;
    unsigned short* h_f = G_b + (size_t)Tn * Bn * G4;
    unsigned short* h_b = h_f + (size_t)Tn * Bn * 128;
    float* feats = (float*)(h_b + (size_t)Tn * Bn * 128);
    unsigned char* whh8 = (unsigned char*)(feats + (size_t)Tn * Bn * 9);

    k_wcvt<<<512, 256, 0, stream>>>(w_hh_f, w_hh_b, whh8);
    k_inproj<<<dim3(512, 4, 2), 256, 0, stream>>>(sent, embed,
        w_ih_f, b_ih_f, b_hh_f, w_ih_b, b_ih_b, b_hh_b, G_f, G_b);
    k_lstm<<<dim3(64, 2), 512, 0, stream>>>(whh8, G_f, G_b, h_f, h_b);
    k_feats<<<256, 256, 0, stream>>>(h_f, h_b, w_out, b_out, feats);
    k_viterbi<<<64, 64, 0, stream>>>(feats, trans, out);
}

// Round 5
// 779.924 us; speedup vs baseline: 1.8868x; 1.0460x over previous
//
#include <hip/hip_runtime.h>
#include <hip/hip_bf16.h>

#define Tn 1024
#define Bn 64
#define En 128
#define G4 512
#define NEGV -10000.0f

typedef short bh8 __attribute__((ext_vector_type(8)));
typedef float fl4 __attribute__((ext_vector_type(4)));
typedef int i8v __attribute__((ext_vector_type(8)));

// ---------- fast transcendental primitives ----------
#if __has_builtin(__builtin_amdgcn_exp2f)
#define EXP2(x) __builtin_amdgcn_exp2f(x)
#else
#define EXP2(x) exp2f(x)
#endif
#if __has_builtin(__builtin_amdgcn_rcpf)
#define RCP(x) __builtin_amdgcn_rcpf(x)
#else
#define RCP(x) (1.0f / (x))
#endif

#define LOG2E  1.4426950408889634f
#define LOG2E2 2.8853900817779268f

// ---------- bf16 helpers ----------
__device__ __forceinline__ float bf2f(unsigned short u) {
    unsigned int v = ((unsigned int)u) << 16;
    float f;
    __builtin_memcpy(&f, &v, 4);
    return f;
}
__device__ __forceinline__ unsigned short f2bf(float f) {
    unsigned int u;
    __builtin_memcpy(&u, &f, 4);
    u = (u + 0x7fffu + ((u >> 16) & 1u)) >> 16;
    return (unsigned short)u;
}
// hw packed f32x2 -> bf16x2 (RNE, same as manual f2bf)
__device__ __forceinline__ unsigned cvt_pk_bf16(float lo, float hi) {
    unsigned r;
    asm("v_cvt_pk_bf16_f32 %0, %1, %2" : "=v"(r) : "v"(lo), "v"(hi));
    return r;
}
__device__ __forceinline__ unsigned short f2bf_hw(float x) {
    return (unsigned short)(cvt_pk_bf16(x, 0.0f) & 0xffffu);
}
__device__ __forceinline__ float asf(unsigned int u) {
    float f;
    __builtin_memcpy(&f, &u, 4);
    return f;
}
__device__ __forceinline__ float i2f(int u) {
    float f;
    __builtin_memcpy(&f, &u, 4);
    return f;
}
__device__ __forceinline__ int f2i(float f) {
    int u;
    __builtin_memcpy(&u, &f, 4);
    return u;
}

// ---------- fp8 e4m3fn encode ----------
__device__ __forceinline__ unsigned char f8enc(float x) {
#if __has_builtin(__builtin_amdgcn_cvt_pk_fp8_f32)
    int pk = __builtin_amdgcn_cvt_pk_fp8_f32(x, 0.0f, 0, false);
    return (unsigned char)(pk & 0xff);
#else
    // manual OCP e4m3fn (RNE): max 448, min normal 2^-6, subnormal step 2^-9
    unsigned u;
    __builtin_memcpy(&u, &x, 4);
    unsigned s = (u >> 31) << 7;
    float a = fabsf(x);
    if (!(a > 0.0f)) return (unsigned char)s;
    if (a >= 464.0f) return (unsigned char)(s | 0x7E);
    if (a < 0.015625f) {
        int q = (int)rintf(a * 512.0f);
        return (unsigned char)(s | (unsigned)q);
    }
    int ex;
    (void)frexpf(a, &ex);
    int E = ex - 1;
    float t = ldexpf(a, -E);
    int m3 = (int)rintf((t - 1.0f) * 8.0f);
    if (m3 == 8) { m3 = 0; E += 1; }
    if (E > 8) return (unsigned char)(s | 0x7E);
    return (unsigned char)(s | ((unsigned)(E + 7) << 3) | (unsigned)m3);
#endif
}

// lgkm-only barrier: LDS visibility without draining vmcnt.
// imm 0xC07F = vmcnt(63) expcnt(7) lgkmcnt(0).
__device__ __forceinline__ void barrier_lds_only() {
    __builtin_amdgcn_s_waitcnt(0xC07F);
    __builtin_amdgcn_s_barrier();
}

// =====================================================================
// K0: one-time weight conversion whh (fp32 [512][128], both dirs) -> fp8 e4m3
// scaled by 64 (keeps w ~ N(0,0.01) in e4m3's normal range).
// =====================================================================
__global__ __launch_bounds__(256) void k_wcvt(
    const float* __restrict__ wf, const float* __restrict__ wb,
    unsigned char* __restrict__ o)
{
    const int i = blockIdx.x * 256 + threadIdx.x;   // 0 .. 131071
    const float v = (i < 65536) ? wf[i] : wb[i - 65536];
    o[i] = f8enc(v * 64.0f);
}

// =====================================================================
// K1: input projection via bf16 MFMA.
// Weight rows consumed PRE-PERMUTED so N enumerates packed [j][gate]
// (norig = (n&3)*128 + (n>>2)); epilogue stores contiguous across lanes.
// G stored pre-scaled by log2e (i,f,o) / 2*log2e (g).
// R16: staging + epilogue bf16 conversion via v_cvt_pk_bf16_f32 (1 op /
// 2 elems, RNE identical) — cuts per-thread VALU ~900 -> ~250.
// =====================================================================
__global__ __launch_bounds__(256) void k_inproj(
    const int* __restrict__ sent, const float* __restrict__ embed,
    const float* __restrict__ w_ih_f, const float* __restrict__ b_ih_f, const float* __restrict__ b_hh_f,
    const float* __restrict__ w_ih_b, const float* __restrict__ b_ih_b, const float* __restrict__ b_hh_b,
    unsigned short* __restrict__ G_f, unsigned short* __restrict__ G_b)
{
    __shared__ unsigned short Asm[128][136];
    __shared__ unsigned short Bsm[128][136];
    const int tid = threadIdx.x;
    const int dir = blockIdx.z;
    const float* w_ih = dir ? w_ih_b : w_ih_f;
    const float* bi   = dir ? b_ih_b : b_ih_f;
    const float* bh   = dir ? b_hh_b : b_hh_f;
    unsigned short* Gout = dir ? G_b : G_f;

    const int mt = blockIdx.x, nt = blockIdx.y;
    const int r0 = mt * 128, n0 = nt * 128;

    const int srow = tid >> 1;
    const int ch = (tid & 1) * 64;
    {
        const int rg = r0 + srow;
        const int tt = rg >> 6, bb = rg & 63;
        const int tok = sent[bb * Tn + tt];
        const int np = n0 + srow;                          // packed row index
        const int norig = ((np & 3) << 7) + (np >> 2);     // original w_ih row
        const float* ar = embed + (size_t)tok * En + ch;
        const float* br = w_ih + (size_t)norig * En + ch;
#pragma unroll
        for (int i = 0; i < 64; i += 4) {
            float4 v = *(const float4*)(ar + i);
            *(unsigned*)&Asm[srow][ch + i]     = cvt_pk_bf16(v.x, v.y);
            *(unsigned*)&Asm[srow][ch + i + 2] = cvt_pk_bf16(v.z, v.w);
            float4 u = *(const float4*)(br + i);
            *(unsigned*)&Bsm[srow][ch + i]     = cvt_pk_bf16(u.x, u.y);
            *(unsigned*)&Bsm[srow][ch + i + 2] = cvt_pk_bf16(u.z, u.w);
        }
    }
    __syncthreads();

    const int w = tid >> 6, lane = tid & 63;
    const int ln = lane & 15, lq = lane >> 4;
    const int nwb = w * 32;

    fl4 acc[8][2];
#pragma unroll
    for (int mi = 0; mi < 8; ++mi)
#pragma unroll
        for (int ni = 0; ni < 2; ++ni) acc[mi][ni] = (fl4){0.f, 0.f, 0.f, 0.f};

#pragma unroll
    for (int kt = 0; kt < 4; ++kt) {
        const int kc = kt * 32 + lq * 8;
        bh8 a[8], bf[2];
#pragma unroll
        for (int mi = 0; mi < 8; ++mi) a[mi] = *(const bh8*)&Asm[mi * 16 + ln][kc];
#pragma unroll
        for (int ni = 0; ni < 2; ++ni) bf[ni] = *(const bh8*)&Bsm[nwb + ni * 16 + ln][kc];
#pragma unroll
        for (int mi = 0; mi < 8; ++mi)
#pragma unroll
            for (int ni = 0; ni < 2; ++ni)
                acc[mi][ni] = __builtin_amdgcn_mfma_f32_16x16x32_bf16(a[mi], bf[ni], acc[mi][ni], 0, 0, 0);
    }

    float bias[2], gsc[2];
#pragma unroll
    for (int ni = 0; ni < 2; ++ni) {
        const int np = n0 + nwb + ni * 16 + ln;            // packed index j*4+gate
        const int norig = ((np & 3) << 7) + (np >> 2);
        bias[ni] = bi[norig] + bh[norig];
        gsc[ni] = ((np & 3) == 2) ? LOG2E2 : LOG2E;        // gate g gets 2*log2e
    }
#pragma unroll
    for (int mi = 0; mi < 8; ++mi)
#pragma unroll
        for (int ni = 0; ni < 2; ++ni) {
            const int np = n0 + nwb + ni * 16 + ln;        // store position directly
#pragma unroll
            for (int rg = 0; rg < 4; ++rg) {
                const int m = mi * 16 + lq * 4 + rg;
                const size_t r = (size_t)(r0 + m);
                Gout[(r << 9) + np] = f2bf_hw((acc[mi][ni][rg] + bias[ni]) * gsc[ni]);
            }
        }
}

// =====================================================================
// K2: LSTM recurrence — UNCHANGED from R15 (392.8 us, latency-chain
// bound; issue cuts proven ineffective, structure changes proven
// counterproductive). Protecting this version.
// =====================================================================
__global__ __launch_bounds__(512, 2) void k_lstm(
    const unsigned char* __restrict__ whh8,
    const unsigned short* __restrict__ G_f, const unsigned short* __restrict__ G_b,
    unsigned short* __restrict__ h_f, unsigned short* __restrict__ h_b)
{
    const int tid = threadIdx.x;
    const int w = tid >> 6;
    const int lane = tid & 63;
    const int ln = lane & 15;
    const int quad = lane >> 4;
    const int b = blockIdx.x;           // batch
    const int dir = blockIdx.y;
    const unsigned short* Gd = dir ? G_b : G_f;
    unsigned short* ho = dir ? h_b : h_f;

    const int j = w * 16 + ln;          // this lane's h index (gate column)

    __shared__ __align__(16) unsigned char hls8[2][128];   // fp8 h (x16), double-buffered

    // ---- weights (B-frags): lane provides B[k=quad*32+i][n=ln] = W8[q*128+j][quad*32+i]
    const unsigned char* wb8 = whh8 + (size_t)dir * 65536 + quad * 32;
    const i8v w0 = *(const i8v*)(wb8 + ((size_t)(0 * 128 + j) << 7));
    const i8v w1 = *(const i8v*)(wb8 + ((size_t)(1 * 128 + j) << 7));
    const i8v w2 = *(const i8v*)(wb8 + ((size_t)(2 * 128 + j) << 7));
    const i8v w3 = *(const i8v*)(wb8 + ((size_t)(3 * 128 + j) << 7));

    // zero both h buffers (2*128 fp8 = 64 dwords); fp8 0x00 == 0.0
    if (tid < 64) ((unsigned*)hls8)[tid] = 0u;
    float c = 0.0f;
    __syncthreads();

    // ---- G pipeline preload: slot u = packed gates [i|f] [g|o] of step u ----
    uint2 gp[4];
#pragma unroll
    for (int u = 0; u < 4; ++u) {
        const int tt = dir ? (Tn - 1 - u) : u;
        gp[u] = *(const uint2*)(Gd + (((size_t)tt * Bn + b) << 9) + (j << 2));
    }

    const float dsL  = 0.0009765625f * LOG2E;    // 1/(64*16) descale, log2e-folded
    const float ds2L = 0.0009765625f * LOG2E2;   // g-gate descale

    // ---- lane-constant activation params (quad q owns gate q) ----
    const float cds = (quad == 2) ? ds2L : -dsL;
    const unsigned gsign = (quad == 2) ? 0u : 0x80000000u;
    const int gshift = (quad & 1) ? 0 : 16;
    const int bp0 = (0 * 16 + ln) << 2;     // bpermute byte addrs (lane*4)
    const int bp1 = (1 * 16 + ln) << 2;
    const int bp2 = (2 * 16 + ln) << 2;
    const int bp3 = (3 * 16 + ln) << 2;

    for (int blk = 0; blk < Tn / 4; ++blk) {
#pragma unroll
        for (int u = 0; u < 4; ++u) {
            const int s = blk * 4 + u;
            const int t = dir ? (Tn - 1 - s) : s;
            const int p = u & 1;          // h buffer parity (blk*4 is even)

            // consume slot u (loaded at step s-4)
            const uint2 gv = gp[u];

            // prefetch step s+4 into slot u (static index -> stays in regs)
            if (s + 4 < Tn) {
                const int tt = dir ? (Tn - 5 - s) : (s + 4);
                gp[u] = *(const uint2*)(Gd + (((size_t)tt * Bn + b) << 9) + (j << 2));
            }

            // ---- A-frag: 32 fp8 of h, k = quad*32 .. +32 (broadcast across ln)
            const i8v ha = *(const i8v*)&hls8[p][quad * 32];

            // ---- 4 INDEPENDENT K=128 fp8 MFMAs: aq = dot(h, W[q*128+j]) * 1024
            const fl4 z = (fl4){0.f, 0.f, 0.f, 0.f};
            fl4 a0 = __builtin_amdgcn_mfma_scale_f32_16x16x128_f8f6f4(
                         ha, w0, z, 0, 0, 0, 0x7F7F7F7F, 0, 0x7F7F7F7F);
            fl4 a1 = __builtin_amdgcn_mfma_scale_f32_16x16x128_f8f6f4(
                         ha, w1, z, 0, 0, 0, 0x7F7F7F7F, 0, 0x7F7F7F7F);
            fl4 a2 = __builtin_amdgcn_mfma_scale_f32_16x16x128_f8f6f4(
                         ha, w2, z, 0, 0, 0, 0x7F7F7F7F, 0, 0x7F7F7F7F);
            fl4 a3 = __builtin_amdgcn_mfma_scale_f32_16x16x128_f8f6f4(
                         ha, w3, z, 0, 0, 0, 0x7F7F7F7F, 0, 0x7F7F7F7F);

            // ---- quad-specialized activation: own gate only ----
            float a01 = (quad & 1) ? a1[0] : a0[0];
            float a23 = (quad & 1) ? a3[0] : a2[0];
            float aown = (quad & 2) ? a23 : a01;
            unsigned wsel = (quad & 2) ? gv.y : gv.x;
            unsigned gb = ((wsel << gshift) & 0xffff0000u) ^ gsign;
            float pre = __builtin_fmaf(aown, cds, asf(gb));
            float tq = RCP(1.0f + EXP2(pre));
            // gather all four gate results to every lane (wave crossbar)
            int tqi = f2i(tq);
            float iv = i2f(__builtin_amdgcn_ds_bpermute(bp0, tqi));
            float fv = i2f(__builtin_amdgcn_ds_bpermute(bp1, tqi));
            float tg = i2f(__builtin_amdgcn_ds_bpermute(bp2, tqi));
            float ov = i2f(__builtin_amdgcn_ds_bpermute(bp3, tqi));
            float gvv = __builtin_fmaf(-2.0f, tg, 1.0f);
            c = __builtin_fmaf(fv, c, iv * gvv);
            float r2 = RCP(1.0f + EXP2(c * LOG2E2));
            float hn = ov * __builtin_fmaf(-2.0f, r2, 1.0f);

            // ---- h writes (quad==0 lanes cover all 128 j): LDS fp8(x16) + global bf16
            if (quad == 0) {
                hls8[1 - p][j] = f8enc(hn * 16.0f);
                ho[(((size_t)t * Bn + b) << 7) + j] = f2bf(hn);
            }

            barrier_lds_only();
        }
    }
}

// =====================================================================
// K3: feats.
// R16: output layout TRANSPOSED to featsT[b][t][n] (b*9216 + t*9 + n)
// so k_viterbi's per-batch staging becomes contiguous float4 loads.
// =====================================================================
__global__ __launch_bounds__(256) void k_feats(
    const unsigned short* __restrict__ h_f, const unsigned short* __restrict__ h_b,
    const float* __restrict__ w_out, const float* __restrict__ b_out,
    float* __restrict__ feats)
{
    __shared__ float wl[256][12];
    __shared__ float bl[12];
    const int tid = threadIdx.x;
#pragma unroll
    for (int s = 0; s < 9; ++s) wl[tid][s] = w_out[s * 256 + tid];
#pragma unroll
    for (int s = 9; s < 12; ++s) wl[tid][s] = 0.0f;
    if (tid < 12) bl[tid] = (tid < 9) ? b_out[tid] : 0.0f;
    __syncthreads();

    const int r = blockIdx.x * 256 + tid;
    const unsigned short* hfr = h_f + (size_t)r * 128;
    const unsigned short* hbr = h_b + (size_t)r * 128;
    float acc[12];
#pragma unroll
    for (int k = 0; k < 12; ++k) acc[k] = bl[k];

    for (int ch = 0; ch < 32; ++ch) {
        const unsigned short* src = (ch < 16) ? (hfr + ch * 8) : (hbr + (ch - 16) * 8);
        uint4 hv = *(const uint4*)src;
        unsigned int hw0 = hv.x, hw1 = hv.y, hw2 = hv.z, hw3 = hv.w;
        const int jb = ch * 8;
#pragma unroll
        for (int q = 0; q < 8; ++q) {
            unsigned int word = (q < 2) ? hw0 : ((q < 4) ? hw1 : ((q < 6) ? hw2 : hw3));
            unsigned short hs = (q & 1) ? (unsigned short)(word >> 16) : (unsigned short)(word & 0xffff);
            float hf = bf2f(hs);
            const float* wrp = &wl[jb + q][0];
            float4 w0 = *(const float4*)(wrp);
            float4 w1 = *(const float4*)(wrp + 4);
            float4 w2 = *(const float4*)(wrp + 8);
            acc[0] += hf * w0.x; acc[1] += hf * w0.y; acc[2] += hf * w0.z; acc[3] += hf * w0.w;
            acc[4] += hf * w1.x; acc[5] += hf * w1.y; acc[6] += hf * w1.z; acc[7] += hf * w1.w;
            acc[8] += hf * w2.x; acc[9] += hf * w2.y; acc[10] += hf * w2.z; acc[11] += hf * w2.w;
        }
    }
    const int t = r >> 6, b = r & 63;                 // r = t*64 + b
    float* fr = feats + (size_t)b * 9216 + (size_t)t * 9;
#pragma unroll
    for (int k = 0; k < 9; ++k) fr[k] = acc[k];
}

// =====================================================================
// K4: Viterbi — R16: argmax OFF the recurrence chain.
// delta(t+1) needs only the MAX: nested fmaxf triples fuse to 2
// dependent v_max3_f32 (~8-16 cyc) instead of the 8-deep sequential
// compare-select scan (~100+ cyc) the backpointer shared. The argmax
// (backpointer) is a tournament computed OFF-chain (overlaps next
// step's shfl latency). Tie semantics identical: tournament keeps the
// left (lower-index) operand on ties == sequential first-max.
// Staging: featsT[b] is contiguous -> float4 coalesced loads.
// =====================================================================
__global__ __launch_bounds__(64) void k_viterbi(
    const float* __restrict__ feats, const float* __restrict__ trans,
    float* __restrict__ out)
{
    __shared__ __align__(16) unsigned char bp[1024 * 16];
    __shared__ __align__(16) float fl[1024 * 9];
    __shared__ unsigned char pt[1024];

    const int b = blockIdx.x, tid = threadIdx.x;

    // coalesced staging: featsT[b][0..9215] contiguous, 16B per lane
    {
        const float4* fsrc = (const float4*)(feats + (size_t)b * 9216);
        float4* fdst = (float4*)fl;
        for (int i = tid; i < 2304; i += 64) fdst[i] = fsrc[i];
    }

    const int n9 = (tid < 9) ? tid : 8;   // clamp so inactive lanes stay valid
    float trn[9];
#pragma unroll
    for (int p = 0; p < 9; ++p) trn[p] = trans[n9 * 9 + p];
    float trs = (tid < 9) ? trans[8 * 9 + tid] : -3.0e38f;

    float delta = (n9 == 7) ? 0.0f : NEGV;   // START=7
    __syncthreads();

    float fnext = fl[n9];                     // feats for t=0
    for (int t = 0; t < 1024; ++t) {
        // gather all 9 previous deltas (in-register wave crossbar)
        float d0 = __shfl(delta, 0, 64);
        float d1 = __shfl(delta, 1, 64);
        float d2 = __shfl(delta, 2, 64);
        float d3 = __shfl(delta, 3, 64);
        float d4 = __shfl(delta, 4, 64);
        float d5 = __shfl(delta, 5, 64);
        float d6 = __shfl(delta, 6, 64);
        float d7 = __shfl(delta, 7, 64);
        float d8 = __shfl(delta, 8, 64);
        float fhere = fnext;
        if (t < 1023) fnext = fl[(t + 1) * 9 + n9];   // prefetch next step

        float s0 = d0 + trn[0], s1 = d1 + trn[1], s2 = d2 + trn[2];
        float s3 = d3 + trn[3], s4 = d4 + trn[4], s5 = d5 + trn[5];
        float s6 = d6 + trn[6], s7 = d7 + trn[7], s8 = d8 + trn[8];

        // recurrence chain: max via two fused max3 levels (exact)
        float m012 = fmaxf(fmaxf(s0, s1), s2);
        float m345 = fmaxf(fmaxf(s3, s4), s5);
        float m678 = fmaxf(fmaxf(s6, s7), s8);
        float m = fmaxf(fmaxf(m012, m345), m678);
        delta = m + fhere;

        // backpointer: off-chain tournament, keep-left-on-tie == first max
        float v01 = (s1 > s0) ? s1 : s0; int a01 = (s1 > s0) ? 1 : 0;
        float v23 = (s3 > s2) ? s3 : s2; int a23 = (s3 > s2) ? 3 : 2;
        float v45 = (s5 > s4) ? s5 : s4; int a45 = (s5 > s4) ? 5 : 4;
        float v67 = (s7 > s6) ? s7 : s6; int a67 = (s7 > s6) ? 7 : 6;
        float v03 = (v23 > v01) ? v23 : v01; int a03 = (v23 > v01) ? a23 : a01;
        float v47 = (v67 > v45) ? v67 : v45; int a47 = (v67 > v45) ? a67 : a45;
        float v07 = (v47 > v03) ? v47 : v03; int a07 = (v47 > v03) ? a47 : a03;
        int am = (s8 > v07) ? 8 : a07;

        if (tid < 9) bp[t * 16 + tid] = (unsigned char)am;
    }

    float tv = (tid < 9) ? (delta + trs) : -3.0e38f;
    int bi = tid;
#pragma unroll
    for (int off = 8; off >= 1; off >>= 1) {
        float ov = __shfl_down(tv, off, 64);
        int oi = __shfl_down(bi, off, 64);
        if (ov > tv || (ov == tv && oi < bi)) { tv = ov; bi = oi; }
    }
    int best = __shfl(bi, 0, 64);
    if (tid == 0) out[b] = tv;

    if (tid == 0) {
        int tag = best;
        for (int t0 = 1023; t0 >= 0; t0 -= 8) {
            uint4 rows[8];
#pragma unroll
            for (int i = 0; i < 8; ++i) rows[i] = *(const uint4*)&bp[(t0 - i) * 16];
#pragma unroll
            for (int i = 0; i < 8; ++i) {
                pt[t0 - i] = (unsigned char)tag;
                uint4 rw = rows[i];
                unsigned int sel = (unsigned int)tag >> 2;
                unsigned int word = (sel == 0) ? rw.x : ((sel == 1) ? rw.y : rw.z);
                tag = (int)((word >> ((tag & 3) * 8)) & 0xffu);
            }
        }
    }
    for (int i = tid; i < 1024; i += 64) {
        out[64 + b * 1024 + i] = (float)pt[i];
    }
}

// =====================================================================
extern "C" void kernel_launch(void* const* d_in, const int* in_sizes, int n_in,
                              void* d_out, int out_size, void* d_ws, size_t ws_size,
                              hipStream_t stream) {
    const int*   sent   = (const int*)d_in[0];
    const float* embed  = (const float*)d_in[1];
    const float* w_ih_f = (const float*)d_in[2];
    const float* w_hh_f = (const float*)d_in[3];
    const float* b_ih_f = (const float*)d_in[4];
    const float* b_hh_f = (const float*)d_in[5];
    const float* w_ih_b = (const float*)d_in[6];
    const float* w_hh_b = (const float*)d_in[7];
    const float* b_ih_b = (const float*)d_in[8];
    const float* b_hh_b = (const float*)d_in[9];
    const float* w_out  = (const float*)d_in[10];
    const float* b_out  = (const float*)d_in[11];
    const float* trans  = (const float*)d_in[12];
    float* out = (float*)d_out;

    unsigned short* G_f = (unsigned short*)d_ws;
    unsigned short* G_b = G_f + (size_t)Tn * Bn * G4;
    unsigned short* h_f = G_b + (size_t)Tn * Bn * G4;
    unsigned short* h_b = h_f + (size_t)Tn * Bn * 128;
    float* feats = (float*)(h_b + (size_t)Tn * Bn * 128);
    unsigned char* whh8 = (unsigned char*)(feats + (size_t)Tn * Bn * 9);

    k_wcvt<<<512, 256, 0, stream>>>(w_hh_f, w_hh_b, whh8);
    k_inproj<<<dim3(512, 4, 2), 256, 0, stream>>>(sent, embed,
        w_ih_f, b_ih_f, b_hh_f, w_ih_b, b_ih_b, b_hh_b, G_f, G_b);
    k_lstm<<<dim3(64, 2), 512, 0, stream>>>(whh8, G_f, G_b, h_f, h_b);
    k_feats<<<256, 256, 0, stream>>>(h_f, h_b, w_out, b_out, feats);
    k_viterbi<<<64, 64, 0, stream>>>(feats, trans, out);
}

// Round 6
// 737.792 us; speedup vs baseline: 1.9945x; 1.0571x over previous
//
#include <hip/hip_runtime.h>
#include <hip/hip_bf16.h>

#define Tn 1024
#define Bn 64
#define En 128
#define G4 512
#define NEGV -10000.0f

typedef short bh8 __attribute__((ext_vector_type(8)));
typedef float fl4 __attribute__((ext_vector_type(4)));
typedef int i8v __attribute__((ext_vector_type(8)));

// ---------- fast transcendental primitives ----------
#if __has_builtin(__builtin_amdgcn_exp2f)
#define EXP2(x) __builtin_amdgcn_exp2f(x)
#else
#define EXP2(x) exp2f(x)
#endif
#if __has_builtin(__builtin_amdgcn_rcpf)
#define RCP(x) __builtin_amdgcn_rcpf(x)
#else
#define RCP(x) (1.0f / (x))
#endif

#define LOG2E  1.4426950408889634f
#define LOG2E2 2.8853900817779268f

// ---------- bf16 helpers ----------
__device__ __forceinline__ float bf2f(unsigned short u) {
    unsigned int v = ((unsigned int)u) << 16;
    float f;
    __builtin_memcpy(&f, &v, 4);
    return f;
}
__device__ __forceinline__ unsigned short f2bf(float f) {
    unsigned int u;
    __builtin_memcpy(&u, &f, 4);
    u = (u + 0x7fffu + ((u >> 16) & 1u)) >> 16;
    return (unsigned short)u;
}
// hw packed f32x2 -> bf16x2 (RNE, same as manual f2bf)
__device__ __forceinline__ unsigned cvt_pk_bf16(float lo, float hi) {
    unsigned r;
    asm("v_cvt_pk_bf16_f32 %0, %1, %2" : "=v"(r) : "v"(lo), "v"(hi));
    return r;
}
__device__ __forceinline__ unsigned short f2bf_hw(float x) {
    return (unsigned short)(cvt_pk_bf16(x, 0.0f) & 0xffffu);
}
__device__ __forceinline__ float asf(unsigned int u) {
    float f;
    __builtin_memcpy(&f, &u, 4);
    return f;
}
__device__ __forceinline__ float i2f(int u) {
    float f;
    __builtin_memcpy(&f, &u, 4);
    return f;
}
__device__ __forceinline__ int f2i(float f) {
    int u;
    __builtin_memcpy(&u, &f, 4);
    return u;
}

// ---------- fp8 e4m3fn encode ----------
__device__ __forceinline__ unsigned char f8enc(float x) {
#if __has_builtin(__builtin_amdgcn_cvt_pk_fp8_f32)
    int pk = __builtin_amdgcn_cvt_pk_fp8_f32(x, 0.0f, 0, false);
    return (unsigned char)(pk & 0xff);
#else
    // manual OCP e4m3fn (RNE): max 448, min normal 2^-6, subnormal step 2^-9
    unsigned u;
    __builtin_memcpy(&u, &x, 4);
    unsigned s = (u >> 31) << 7;
    float a = fabsf(x);
    if (!(a > 0.0f)) return (unsigned char)s;
    if (a >= 464.0f) return (unsigned char)(s | 0x7E);
    if (a < 0.015625f) {
        int q = (int)rintf(a * 512.0f);
        return (unsigned char)(s | (unsigned)q);
    }
    int ex;
    (void)frexpf(a, &ex);
    int E = ex - 1;
    float t = ldexpf(a, -E);
    int m3 = (int)rintf((t - 1.0f) * 8.0f);
    if (m3 == 8) { m3 = 0; E += 1; }
    if (E > 8) return (unsigned char)(s | 0x7E);
    return (unsigned char)(s | ((unsigned)(E + 7) << 3) | (unsigned)m3);
#endif
}

// lgkm-only barrier: LDS visibility without draining vmcnt.
// imm 0xC07F = vmcnt(63) expcnt(7) lgkmcnt(0).
__device__ __forceinline__ void barrier_lds_only() {
    __builtin_amdgcn_s_waitcnt(0xC07F);
    __builtin_amdgcn_s_barrier();
}

// =====================================================================
// K0: one-time weight conversion.
// i < 131072:    whh (fp32 [512][128], both dirs) -> fp8 e4m3 scaled x64.
// i >= 131072:   w_ih (both dirs) -> bf16, PACKED-PERMUTED rows:
//                wihP[dir][np][k] = bf16(w_ih_dir[((np&3)<<7)+(np>>2)][k])
//                so k_inproj's B staging is a raw copy (no cvt, no permute).
// =====================================================================
__global__ __launch_bounds__(256) void k_wcvt(
    const float* __restrict__ wf, const float* __restrict__ wb,
    const float* __restrict__ wih_f, const float* __restrict__ wih_b,
    unsigned char* __restrict__ o, unsigned short* __restrict__ wihP)
{
    const int i = blockIdx.x * 256 + threadIdx.x;   // 0 .. 262143
    if (i < 131072) {
        const float v = (i < 65536) ? wf[i] : wb[i - 65536];
        o[i] = f8enc(v * 64.0f);
    } else {
        const int j = i - 131072;                   // 0 .. 131071
        const int dir = j >> 16;
        const int np = (j >> 7) & 511;
        const int k = j & 127;
        const int norig = ((np & 3) << 7) + (np >> 2);
        const float* w = dir ? wih_b : wih_f;
        wihP[j] = f2bf_hw(w[norig * 128 + k]);
    }
}

// =====================================================================
// K1: input projection via bf16 MFMA — R17 restructure.
// Old: grid (512,4,2), each WG re-staged its A tile (embed gather) =>
// A staged 8x, B re-read 512x => ~512MB of staging reads + cvt VALU.
// New: grid 512 (one WG per 128-row tile). A staged ONCE; loop over the
// 8 (dir,nt) B-chunks with double-buffered LDS B (A 34.8KB + 2x34.8KB).
// B comes pre-converted bf16 packed-permuted from k_wcvt => staging is
// pure uint4 copies. A reads 512MB->32MB; B reads 128MB L2-hot.
// G output bit-identical to R16 (same staged values, same MFMA, same
// bias/gsc, same store positions; pre-scaled by log2e / 2*log2e).
// =====================================================================
__global__ __launch_bounds__(256) void k_inproj(
    const int* __restrict__ sent, const float* __restrict__ embed,
    const unsigned short* __restrict__ wihP,
    const float* __restrict__ b_ih_f, const float* __restrict__ b_hh_f,
    const float* __restrict__ b_ih_b, const float* __restrict__ b_hh_b,
    unsigned short* __restrict__ G_f, unsigned short* __restrict__ G_b)
{
    __shared__ unsigned short Asm[128][136];
    __shared__ unsigned short Bsm[2][128][136];
    const int tid = threadIdx.x;
    const int mt = blockIdx.x;
    const int r0 = mt * 128;

    // ---- stage A once: rows r0..r0+127 of embed[token] as bf16 ----
    {
        const int srow = tid >> 1;
        const int ch = (tid & 1) * 64;
        const int rg = r0 + srow;
        const int tt = rg >> 6, bb = rg & 63;
        const int tok = sent[bb * Tn + tt];
        const float* ar = embed + (size_t)tok * En + ch;
#pragma unroll
        for (int i = 0; i < 64; i += 4) {
            float4 v = *(const float4*)(ar + i);
            *(unsigned*)&Asm[srow][ch + i]     = cvt_pk_bf16(v.x, v.y);
            *(unsigned*)&Asm[srow][ch + i + 2] = cvt_pk_bf16(v.z, v.w);
        }
    }

    // ---- B chunk staging: raw bf16 copy (128 rows x 128 cols) ----
    const int brow = tid >> 1;
    const int bhalf = (tid & 1) * 64;
#define STAGE_B(cidx)                                                          \
    {                                                                          \
        const int d_ = (cidx) >> 2, nt_ = (cidx) & 3, pb_ = (cidx) & 1;        \
        const uint4* s4 = (const uint4*)(wihP + ((size_t)d_ << 16) +           \
                          (size_t)(nt_ * 128 + brow) * 128 + bhalf);           \
        uint4* d4 = (uint4*)&Bsm[pb_][brow][bhalf];                            \
        _Pragma("unroll")                                                      \
        for (int ii = 0; ii < 8; ++ii) d4[ii] = s4[ii];                        \
    }

    STAGE_B(0);
    __syncthreads();

    const int w = tid >> 6, lane = tid & 63;
    const int ln = lane & 15, lq = lane >> 4;
    const int nwb = w * 32;

    for (int cidx = 0; cidx < 8; ++cidx) {
        if (cidx + 1 < 8) STAGE_B(cidx + 1);   // prefetch next chunk (other buffer)
        const int dir = cidx >> 2, nt = cidx & 3, pb = cidx & 1;

        fl4 acc[8][2];
#pragma unroll
        for (int mi = 0; mi < 8; ++mi)
#pragma unroll
            for (int ni = 0; ni < 2; ++ni) acc[mi][ni] = (fl4){0.f, 0.f, 0.f, 0.f};

#pragma unroll
        for (int kt = 0; kt < 4; ++kt) {
            const int kc = kt * 32 + lq * 8;
            bh8 a[8], bf[2];
#pragma unroll
            for (int mi = 0; mi < 8; ++mi) a[mi] = *(const bh8*)&Asm[mi * 16 + ln][kc];
#pragma unroll
            for (int ni = 0; ni < 2; ++ni) bf[ni] = *(const bh8*)&Bsm[pb][nwb + ni * 16 + ln][kc];
#pragma unroll
            for (int mi = 0; mi < 8; ++mi)
#pragma unroll
                for (int ni = 0; ni < 2; ++ni)
                    acc[mi][ni] = __builtin_amdgcn_mfma_f32_16x16x32_bf16(a[mi], bf[ni], acc[mi][ni], 0, 0, 0);
        }

        const float* bi = dir ? b_ih_b : b_ih_f;
        const float* bh = dir ? b_hh_b : b_hh_f;
        unsigned short* Gout = dir ? G_b : G_f;

        float bias[2], gsc[2];
#pragma unroll
        for (int ni = 0; ni < 2; ++ni) {
            const int np = nt * 128 + nwb + ni * 16 + ln;   // packed index j*4+gate
            const int norig = ((np & 3) << 7) + (np >> 2);
            bias[ni] = bi[norig] + bh[norig];
            gsc[ni] = ((np & 3) == 2) ? LOG2E2 : LOG2E;     // gate g gets 2*log2e
        }
#pragma unroll
        for (int mi = 0; mi < 8; ++mi)
#pragma unroll
            for (int ni = 0; ni < 2; ++ni) {
                const int np = nt * 128 + nwb + ni * 16 + ln;
#pragma unroll
                for (int rg = 0; rg < 4; ++rg) {
                    const int m = mi * 16 + lq * 4 + rg;
                    const size_t r = (size_t)(r0 + m);
                    Gout[(r << 9) + np] = f2bf_hw((acc[mi][ni][rg] + bias[ni]) * gsc[ni]);
                }
            }

        __syncthreads();   // chunk done: staged buffer ready, old buffer free
    }
#undef STAGE_B
}

// =====================================================================
// K2: LSTM recurrence — UNCHANGED from R15 (392.8 us; latency-chain
// bound: issue cuts proven low-yield, dual-chain-per-CU proven
// counterproductive in R13). Protecting this version.
// =====================================================================
__global__ __launch_bounds__(512, 2) void k_lstm(
    const unsigned char* __restrict__ whh8,
    const unsigned short* __restrict__ G_f, const unsigned short* __restrict__ G_b,
    unsigned short* __restrict__ h_f, unsigned short* __restrict__ h_b)
{
    const int tid = threadIdx.x;
    const int w = tid >> 6;
    const int lane = tid & 63;
    const int ln = lane & 15;
    const int quad = lane >> 4;
    const int b = blockIdx.x;           // batch
    const int dir = blockIdx.y;
    const unsigned short* Gd = dir ? G_b : G_f;
    unsigned short* ho = dir ? h_b : h_f;

    const int j = w * 16 + ln;          // this lane's h index (gate column)

    __shared__ __align__(16) unsigned char hls8[2][128];   // fp8 h (x16), double-buffered

    // ---- weights (B-frags): lane provides B[k=quad*32+i][n=ln] = W8[q*128+j][quad*32+i]
    const unsigned char* wb8 = whh8 + (size_t)dir * 65536 + quad * 32;
    const i8v w0 = *(const i8v*)(wb8 + ((size_t)(0 * 128 + j) << 7));
    const i8v w1 = *(const i8v*)(wb8 + ((size_t)(1 * 128 + j) << 7));
    const i8v w2 = *(const i8v*)(wb8 + ((size_t)(2 * 128 + j) << 7));
    const i8v w3 = *(const i8v*)(wb8 + ((size_t)(3 * 128 + j) << 7));

    // zero both h buffers (2*128 fp8 = 64 dwords); fp8 0x00 == 0.0
    if (tid < 64) ((unsigned*)hls8)[tid] = 0u;
    float c = 0.0f;
    __syncthreads();

    // ---- G pipeline preload: slot u = packed gates [i|f] [g|o] of step u ----
    uint2 gp[4];
#pragma unroll
    for (int u = 0; u < 4; ++u) {
        const int tt = dir ? (Tn - 1 - u) : u;
        gp[u] = *(const uint2*)(Gd + (((size_t)tt * Bn + b) << 9) + (j << 2));
    }

    const float dsL  = 0.0009765625f * LOG2E;    // 1/(64*16) descale, log2e-folded
    const float ds2L = 0.0009765625f * LOG2E2;   // g-gate descale

    // ---- lane-constant activation params (quad q owns gate q) ----
    const float cds = (quad == 2) ? ds2L : -dsL;
    const unsigned gsign = (quad == 2) ? 0u : 0x80000000u;
    const int gshift = (quad & 1) ? 0 : 16;
    const int bp0 = (0 * 16 + ln) << 2;     // bpermute byte addrs (lane*4)
    const int bp1 = (1 * 16 + ln) << 2;
    const int bp2 = (2 * 16 + ln) << 2;
    const int bp3 = (3 * 16 + ln) << 2;

    for (int blk = 0; blk < Tn / 4; ++blk) {
#pragma unroll
        for (int u = 0; u < 4; ++u) {
            const int s = blk * 4 + u;
            const int t = dir ? (Tn - 1 - s) : s;
            const int p = u & 1;          // h buffer parity (blk*4 is even)

            // consume slot u (loaded at step s-4)
            const uint2 gv = gp[u];

            // prefetch step s+4 into slot u (static index -> stays in regs)
            if (s + 4 < Tn) {
                const int tt = dir ? (Tn - 5 - s) : (s + 4);
                gp[u] = *(const uint2*)(Gd + (((size_t)tt * Bn + b) << 9) + (j << 2));
            }

            // ---- A-frag: 32 fp8 of h, k = quad*32 .. +32 (broadcast across ln)
            const i8v ha = *(const i8v*)&hls8[p][quad * 32];

            // ---- 4 INDEPENDENT K=128 fp8 MFMAs: aq = dot(h, W[q*128+j]) * 1024
            const fl4 z = (fl4){0.f, 0.f, 0.f, 0.f};
            fl4 a0 = __builtin_amdgcn_mfma_scale_f32_16x16x128_f8f6f4(
                         ha, w0, z, 0, 0, 0, 0x7F7F7F7F, 0, 0x7F7F7F7F);
            fl4 a1 = __builtin_amdgcn_mfma_scale_f32_16x16x128_f8f6f4(
                         ha, w1, z, 0, 0, 0, 0x7F7F7F7F, 0, 0x7F7F7F7F);
            fl4 a2 = __builtin_amdgcn_mfma_scale_f32_16x16x128_f8f6f4(
                         ha, w2, z, 0, 0, 0, 0x7F7F7F7F, 0, 0x7F7F7F7F);
            fl4 a3 = __builtin_amdgcn_mfma_scale_f32_16x16x128_f8f6f4(
                         ha, w3, z, 0, 0, 0, 0x7F7F7F7F, 0, 0x7F7F7F7F);

            // ---- quad-specialized activation: own gate only ----
            float a01 = (quad & 1) ? a1[0] : a0[0];
            float a23 = (quad & 1) ? a3[0] : a2[0];
            float aown = (quad & 2) ? a23 : a01;
            unsigned wsel = (quad & 2) ? gv.y : gv.x;
            unsigned gb = ((wsel << gshift) & 0xffff0000u) ^ gsign;
            float pre = __builtin_fmaf(aown, cds, asf(gb));
            float tq = RCP(1.0f + EXP2(pre));
            // gather all four gate results to every lane (wave crossbar)
            int tqi = f2i(tq);
            float iv = i2f(__builtin_amdgcn_ds_bpermute(bp0, tqi));
            float fv = i2f(__builtin_amdgcn_ds_bpermute(bp1, tqi));
            float tg = i2f(__builtin_amdgcn_ds_bpermute(bp2, tqi));
            float ov = i2f(__builtin_amdgcn_ds_bpermute(bp3, tqi));
            float gvv = __builtin_fmaf(-2.0f, tg, 1.0f);
            c = __builtin_fmaf(fv, c, iv * gvv);
            float r2 = RCP(1.0f + EXP2(c * LOG2E2));
            float hn = ov * __builtin_fmaf(-2.0f, r2, 1.0f);

            // ---- h writes (quad==0 lanes cover all 128 j): LDS fp8(x16) + global bf16
            if (quad == 0) {
                hls8[1 - p][j] = f8enc(hn * 16.0f);
                ho[(((size_t)t * Bn + b) << 7) + j] = f2bf(hn);
            }

            barrier_lds_only();
        }
    }
}

// =====================================================================
// K3: feats. Output layout featsT[b][t][n] (b*9216 + t*9 + n) so
// k_viterbi's per-batch staging is contiguous float4 loads.
// =====================================================================
__global__ __launch_bounds__(256) void k_feats(
    const unsigned short* __restrict__ h_f, const unsigned short* __restrict__ h_b,
    const float* __restrict__ w_out, const float* __restrict__ b_out,
    float* __restrict__ feats)
{
    __shared__ float wl[256][12];
    __shared__ float bl[12];
    const int tid = threadIdx.x;
#pragma unroll
    for (int s = 0; s < 9; ++s) wl[tid][s] = w_out[s * 256 + tid];
#pragma unroll
    for (int s = 9; s < 12; ++s) wl[tid][s] = 0.0f;
    if (tid < 12) bl[tid] = (tid < 9) ? b_out[tid] : 0.0f;
    __syncthreads();

    const int r = blockIdx.x * 256 + tid;
    const unsigned short* hfr = h_f + (size_t)r * 128;
    const unsigned short* hbr = h_b + (size_t)r * 128;
    float acc[12];
#pragma unroll
    for (int k = 0; k < 12; ++k) acc[k] = bl[k];

    for (int ch = 0; ch < 32; ++ch) {
        const unsigned short* src = (ch < 16) ? (hfr + ch * 8) : (hbr + (ch - 16) * 8);
        uint4 hv = *(const uint4*)src;
        unsigned int hw0 = hv.x, hw1 = hv.y, hw2 = hv.z, hw3 = hv.w;
        const int jb = ch * 8;
#pragma unroll
        for (int q = 0; q < 8; ++q) {
            unsigned int word = (q < 2) ? hw0 : ((q < 4) ? hw1 : ((q < 6) ? hw2 : hw3));
            unsigned short hs = (q & 1) ? (unsigned short)(word >> 16) : (unsigned short)(word & 0xffff);
            float hf = bf2f(hs);
            const float* wrp = &wl[jb + q][0];
            float4 w0 = *(const float4*)(wrp);
            float4 w1 = *(const float4*)(wrp + 4);
            float4 w2 = *(const float4*)(wrp + 8);
            acc[0] += hf * w0.x; acc[1] += hf * w0.y; acc[2] += hf * w0.z; acc[3] += hf * w0.w;
            acc[4] += hf * w1.x; acc[5] += hf * w1.y; acc[6] += hf * w1.z; acc[7] += hf * w1.w;
            acc[8] += hf * w2.x; acc[9] += hf * w2.y; acc[10] += hf * w2.z; acc[11] += hf * w2.w;
        }
    }
    const int t = r >> 6, b = r & 63;                 // r = t*64 + b
    float* fr = feats + (size_t)b * 9216 + (size_t)t * 9;
#pragma unroll
    for (int k = 0; k < 9; ++k) fr[k] = acc[k];
}

// =====================================================================
// K4: Viterbi (R16: register deltas + shfl gather, max3 chain,
// off-chain backpointer tournament, coalesced featsT staging).
// =====================================================================
__global__ __launch_bounds__(64) void k_viterbi(
    const float* __restrict__ feats, const float* __restrict__ trans,
    float* __restrict__ out)
{
    __shared__ __align__(16) unsigned char bp[1024 * 16];
    __shared__ __align__(16) float fl[1024 * 9];
    __shared__ unsigned char pt[1024];

    const int b = blockIdx.x, tid = threadIdx.x;

    // coalesced staging: featsT[b][0..9215] contiguous, 16B per lane
    {
        const float4* fsrc = (const float4*)(feats + (size_t)b * 9216);
        float4* fdst = (float4*)fl;
        for (int i = tid; i < 2304; i += 64) fdst[i] = fsrc[i];
    }

    const int n9 = (tid < 9) ? tid : 8;   // clamp so inactive lanes stay valid
    float trn[9];
#pragma unroll
    for (int p = 0; p < 9; ++p) trn[p] = trans[n9 * 9 + p];
    float trs = (tid < 9) ? trans[8 * 9 + tid] : -3.0e38f;

    float delta = (n9 == 7) ? 0.0f : NEGV;   // START=7
    __syncthreads();

    float fnext = fl[n9];                     // feats for t=0
    for (int t = 0; t < 1024; ++t) {
        // gather all 9 previous deltas (in-register wave crossbar)
        float d0 = __shfl(delta, 0, 64);
        float d1 = __shfl(delta, 1, 64);
        float d2 = __shfl(delta, 2, 64);
        float d3 = __shfl(delta, 3, 64);
        float d4 = __shfl(delta, 4, 64);
        float d5 = __shfl(delta, 5, 64);
        float d6 = __shfl(delta, 6, 64);
        float d7 = __shfl(delta, 7, 64);
        float d8 = __shfl(delta, 8, 64);
        float fhere = fnext;
        if (t < 1023) fnext = fl[(t + 1) * 9 + n9];   // prefetch next step

        float s0 = d0 + trn[0], s1 = d1 + trn[1], s2 = d2 + trn[2];
        float s3 = d3 + trn[3], s4 = d4 + trn[4], s5 = d5 + trn[5];
        float s6 = d6 + trn[6], s7 = d7 + trn[7], s8 = d8 + trn[8];

        // recurrence chain: max via fused max3 levels (exact)
        float m012 = fmaxf(fmaxf(s0, s1), s2);
        float m345 = fmaxf(fmaxf(s3, s4), s5);
        float m678 = fmaxf(fmaxf(s6, s7), s8);
        float m = fmaxf(fmaxf(m012, m345), m678);
        delta = m + fhere;

        // backpointer: off-chain tournament, keep-left-on-tie == first max
        float v01 = (s1 > s0) ? s1 : s0; int a01 = (s1 > s0) ? 1 : 0;
        float v23 = (s3 > s2) ? s3 : s2; int a23 = (s3 > s2) ? 3 : 2;
        float v45 = (s5 > s4) ? s5 : s4; int a45 = (s5 > s4) ? 5 : 4;
        float v67 = (s7 > s6) ? s7 : s6; int a67 = (s7 > s6) ? 7 : 6;
        float v03 = (v23 > v01) ? v23 : v01; int a03 = (v23 > v01) ? a23 : a01;
        float v47 = (v67 > v45) ? v67 : v45; int a47 = (v67 > v45) ? a67 : a45;
        float v07 = (v47 > v03) ? v47 : v03; int a07 = (v47 > v03) ? a47 : a03;
        int am = (s8 > v07) ? 8 : a07;

        if (tid < 9) bp[t * 16 + tid] = (unsigned char)am;
    }

    float tv = (tid < 9) ? (delta + trs) : -3.0e38f;
    int bi = tid;
#pragma unroll
    for (int off = 8; off >= 1; off >>= 1) {
        float ov = __shfl_down(tv, off, 64);
        int oi = __shfl_down(bi, off, 64);
        if (ov > tv || (ov == tv && oi < bi)) { tv = ov; bi = oi; }
    }
    int best = __shfl(bi, 0, 64);
    if (tid == 0) out[b] = tv;

    if (tid == 0) {
        int tag = best;
        for (int t0 = 1023; t0 >= 0; t0 -= 8) {
            uint4 rows[8];
#pragma unroll
            for (int i = 0; i < 8; ++i) rows[i] = *(const uint4*)&bp[(t0 - i) * 16];
#pragma unroll
            for (int i = 0; i < 8; ++i) {
                pt[t0 - i] = (unsigned char)tag;
                uint4 rw = rows[i];
                unsigned int sel = (unsigned int)tag >> 2;
                unsigned int word = (sel == 0) ? rw.x : ((sel == 1) ? rw.y : rw.z);
                tag = (int)((word >> ((tag & 3) * 8)) & 0xffu);
            }
        }
    }
    for (int i = tid; i < 1024; i += 64) {
        out[64 + b * 1024 + i] = (float)pt[i];
    }
}

// =====================================================================
extern "C" void kernel_launch(void* const* d_in, const int* in_sizes, int n_in,
                              void* d_out, int out_size, void* d_ws, size_t ws_size,
                              hipStream_t stream) {
    const int*   sent   = (const int*)d_in[0];
    const float* embed  = (const float*)d_in[1];
    const float* w_ih_f = (const float*)d_in[2];
    const float* w_hh_f = (const float*)d_in[3];
    const float* b_ih_f = (const float*)d_in[4];
    const float* b_hh_f = (const float*)d_in[5];
    const float* w_ih_b = (const float*)d_in[6];
    const float* w_hh_b = (const float*)d_in[7];
    const float* b_ih_b = (const float*)d_in[8];
    const float* b_hh_b = (const float*)d_in[9];
    const float* w_out  = (const float*)d_in[10];
    const float* b_out  = (const float*)d_in[11];
    const float* trans  = (const float*)d_in[12];
    float* out = (float*)d_out;

    unsigned short* G_f = (unsigned short*)d_ws;
    unsigned short* G_b = G_f + (size_t)Tn * Bn * G4;
    unsigned short* h_f = G_b + (size_t)Tn * Bn * G4;
    unsigned short* h_b = h_f + (size_t)Tn * Bn * 128;
    float* feats = (float*)(h_b + (size_t)Tn * Bn * 128);
    unsigned char* whh8 = (unsigned char*)(feats + (size_t)Tn * Bn * 9);
    unsigned short* wihP = (unsigned short*)(whh8 + 131072);

    k_wcvt<<<1024, 256, 0, stream>>>(w_hh_f, w_hh_b, w_ih_f, w_ih_b, whh8, wihP);
    k_inproj<<<512, 256, 0, stream>>>(sent, embed, wihP,
        b_ih_f, b_hh_f, b_ih_b, b_hh_b, G_f, G_b);
    k_lstm<<<dim3(64, 2), 512, 0, stream>>>(whh8, G_f, G_b, h_f, h_b);
    k_feats<<<256, 256, 0, stream>>>(h_f, h_b, w_out, b_out, feats);
    k_viterbi<<<64, 64, 0, stream>>>(feats, trans, out);
}